// Round 15
// baseline (205.233 us; speedup 1.0000x reference)
//
#include <hip/hip_runtime.h>
#include <math.h>

#define NN 50000
#define NE 800000

#define CH 2500             // nodes per bin chunk
#define C  20               // chunks (20*2500 = 50000)
#define NB1D 16             // e1/e3 dense slices
#define NB2 32              // e2 dense slices
#define CAP 44000           // per-bin capacity (mean 40000, sigma ~195)
#define BSL 2048            // k_bin2 edges per block

typedef unsigned short u16;

__device__ __forceinline__ float lrelu(float x, float s) { return x >= 0.f ? x : s * x; }

// Fused prologue. Blocks [0,64): image matmul. [64,456): per-node pack. [456,...): u16 cvt.
__global__ void k_pre(const float* __restrict__ x, const float* __restrict__ Wl,
                      const float* __restrict__ nodef,
                      const float* __restrict__ W1, const float* __restrict__ al1,
                      const float* __restrict__ ar1,
                      const int* __restrict__ src, const int* __restrict__ dst,
                      float* __restrict__ emb_acc, float* __restrict__ feat4,
                      float* __restrict__ er1, u16* __restrict__ src16,
                      u16* __restrict__ dst16) {
    int bid = blockIdx.x, t = threadIdx.x;
    if (bid < 64) {
        __shared__ float part[8][64];
        int kk = t & 31, rq = t >> 5;
        int r0 = bid * 64;
        float a0 = 0.f, a1 = 0.f;
        if (kk < 30) {
            for (int i = 0; i < 8; ++i) {
                int r = r0 + rq * 8 + i;
                float wv = Wl[r * 30 + kk];
                a0 += x[r] * wv;
                a1 += x[4096 + r] * wv;
            }
        }
        part[rq][kk] = a0;
        part[rq][32 + kk] = a1;
        __syncthreads();
        if (t < 60) {
            int g = t / 30, k = t - g * 30;
            float s = 0.f;
            #pragma unroll
            for (int rr = 0; rr < 8; ++rr) s += part[rr][g * 32 + k];
            atomicAdd(&emb_acc[g * 30 + k], s);
        }
    } else if (bid < 456) {
        __shared__ float sP[6];
        if (t < 6) {
            int c = t >> 1;
            const float* av = (t & 1) ? ar1 : al1;
            float s = 0.f;
            for (int f = 0; f < 80; ++f) s += W1[c * 160 + f] * av[f];
            sP[(t & 1) * 3 + c] = s;
        }
        __syncthreads();
        int b2 = bid - 64;
        int g = b2 / 196;
        int n = (b2 - g * 196) * 256 + t;
        if (n < NN) {
            const float* f = nodef + ((size_t)g * NN + n) * 3;
            float f0 = f[0], f1 = f[1], f2 = f[2];
            *(float4*)(feat4 + ((size_t)g * NN + n) * 4) =
                make_float4(f0, f1, f2, f0 * sP[0] + f1 * sP[1] + f2 * sP[2]);
            er1[g * NN + n] = f0 * sP[3] + f1 * sP[4] + f2 * sP[5];
        }
    } else {
        long flat = ((long)(bid - 456) * 256 + t) * 8;
        if (flat < 2L * 2 * NE) {
            int arr = flat >= 2L * NE;
            long rem = flat - (long)arr * 2 * NE;
            int g = rem >= NE;
            int e = (int)(rem - (long)g * NE);
            const int* ip = (arr ? dst : src) + (size_t)g * NE + e;
            int4 v0 = *(const int4*)ip;
            int4 v1 = *(const int4*)(ip + 4);
            uint4 o;
            o.x = (v0.x & 0xFFFF) | (v0.y << 16);
            o.y = (v0.z & 0xFFFF) | (v0.w << 16);
            o.z = (v1.x & 0xFFFF) | (v1.y << 16);
            o.w = (v1.z & 0xFFFF) | (v1.w << 16);
            *(uint4*)((arr ? dst16 : src16) + (size_t)g * NE + e) = o;
        }
    }
}

// Counting-sort binning; entry carries PARTNER node: (rel<<16)|partner.
// y: 0=dst-binned (partner=src), 1=src-binned (partner=dst). z: graph.
__global__ __launch_bounds__(256) void k_bin2(const u16* __restrict__ dst16,
                                              const u16* __restrict__ src16,
                                              unsigned* __restrict__ gctr,
                                              unsigned* __restrict__ dbin,
                                              unsigned* __restrict__ sbin) {
    __shared__ unsigned wcnt[4][C];
    __shared__ unsigned wbase[4][C];
    __shared__ unsigned wrun[4][C];
    __shared__ unsigned sbase[C];
    int t = threadIdx.x, a = blockIdx.y, g = blockIdx.z;
    int wid = t >> 6;
    if (t < 4 * C) wcnt[t / C][t % C] = 0;
    __syncthreads();
    const u16* ip = (a ? src16 : dst16) + (size_t)g * NE;
    const u16* pp = (a ? dst16 : src16) + (size_t)g * NE;
    unsigned* bin = (a ? sbin : dbin);
    int cbase = (a * 2 + g) * C;
    int bbase = g * C;
    int e0 = blockIdx.x * BSL + t * 8;
    unsigned cj[8], relj[8], pj[8];
    bool act = e0 < NE;
    if (act) {
        uint4 v = *(const uint4*)(ip + e0);
        uint4 pv = *(const uint4*)(pp + e0);
        #pragma unroll
        for (int j = 0; j < 8; ++j) {
            unsigned word = (&v.x)[j >> 1];
            unsigned d = (j & 1) ? (word >> 16) : (word & 0xFFFF);
            unsigned pw = (&pv.x)[j >> 1];
            pj[j] = (j & 1) ? (pw >> 16) : (pw & 0xFFFF);
            unsigned c = d / CH;
            cj[j] = c;
            relj[j] = d - c * CH;
            atomicAdd(&wcnt[wid][c], 1u);
        }
    }
    __syncthreads();
    if (t < C) {
        unsigned s = wcnt[0][t] + wcnt[1][t] + wcnt[2][t] + wcnt[3][t];
        sbase[t] = atomicAdd(&gctr[cbase + t], s);
    }
    __syncthreads();
    if (t < 4 * C) {
        int w2 = t / C, b = t % C;
        unsigned off2 = 0;
        for (int w3 = 0; w3 < w2; ++w3) off2 += wcnt[w3][b];
        wbase[w2][b] = sbase[b] + off2;
        wrun[w2][b] = 0;
    }
    __syncthreads();
    if (act) {
        #pragma unroll
        for (int j = 0; j < 8; ++j) {
            unsigned c = cj[j];
            unsigned slot = atomicAdd(&wrun[wid][c], 1u);
            unsigned pos = wbase[wid][c] + slot;
            if (pos < CAP)
                bin[(size_t)(bbase + c) * CAP + pos] = (relj[j] << 16) | pj[j];
        }
    }
}

// Dense e1: entry = (rel<<16)|src. One feat4 gather per entry. 1024 threads, high occupancy.
__global__ __launch_bounds__(1024) void k_e1d(const unsigned* __restrict__ dbin,
                                              const unsigned* __restrict__ gctr,
                                              const float* __restrict__ feat4,
                                              const float* __restrict__ er1,
                                              float* __restrict__ P) {
    __shared__ float sacc[4 * CH];
    __shared__ float sEr[CH];
    int bx = blockIdx.x, c = blockIdx.y, g = blockIdx.z;
    for (int i = threadIdx.x; i < 4 * CH; i += 1024) sacc[i] = 0.f;
    for (int i = threadIdx.x; i < CH; i += 1024) sEr[i] = er1[(size_t)g * NN + c * CH + i];
    __syncthreads();
    const float* f4 = feat4 + (size_t)g * NN * 4;
    const unsigned* seg = dbin + (size_t)(g * C + c) * CAP;
    unsigned size = gctr[g * C + c];
    unsigned stride = NB1D * 1024;
    for (unsigned i = bx * 1024 + threadIdx.x; i < size; i += stride) {
        unsigned p = seg[i];
        float4 F = *(const float4*)(f4 + (size_t)(p & 0xFFFFu) * 4);
        unsigned r = p >> 16;
        float wv = __expf(lrelu(F.w + sEr[r], 0.2f));
        atomicAdd(&sacc[r], wv * F.x);
        atomicAdd(&sacc[CH + r], wv * F.y);
        atomicAdd(&sacc[2 * CH + r], wv * F.z);
        atomicAdd(&sacc[3 * CH + r], wv);
    }
    __syncthreads();
    float* Pb = P + ((size_t)(g * C + c) * NB1D + bx) * (CH * 4);
    for (int i2 = threadIdx.x; i2 < CH * 4; i2 += 1024)
        Pb[i2] = sacc[(i2 & 3) * CH + (i2 >> 2)];
}

// Dense e2 (den2): entry = (rel<<16)|src. el2[s] gather, er2 chunk preloaded.
__global__ __launch_bounds__(1024) void k_e2d(const unsigned* __restrict__ dbin,
                                              const unsigned* __restrict__ gctr,
                                              const float* __restrict__ el2,
                                              const float* __restrict__ er2iv,
                                              float* __restrict__ P) {
    __shared__ float sden[CH], sEr2[CH];
    int bx = blockIdx.x, c = blockIdx.y, g = blockIdx.z;
    const float* erp = er2iv + ((size_t)g * NN + (size_t)c * CH) * 2;
    for (int i = threadIdx.x; i < CH; i += 1024) { sden[i] = 0.f; sEr2[i] = erp[2 * i]; }
    __syncthreads();
    const float* el = el2 + (size_t)g * NN;
    const unsigned* seg = dbin + (size_t)(g * C + c) * CAP;
    unsigned size = gctr[g * C + c];
    unsigned stride = NB2 * 1024;
    for (unsigned i = bx * 1024 + threadIdx.x; i < size; i += stride) {
        unsigned p = seg[i];
        unsigned r = p >> 16;
        atomicAdd(&sden[r], __expf(lrelu(el[p & 0xFFFFu] + sEr2[r], 0.2f)));
    }
    __syncthreads();
    float* Pb = P + ((size_t)(g * C + c) * NB2 + bx) * CH;
    for (int i2 = threadIdx.x; i2 < CH; i2 += 1024) Pb[i2] = sden[i2];
}

// Dense e3 (q): entry = (rel<<16)|dst. er2iv[d] float2 gather (er2 + invden together).
__global__ __launch_bounds__(1024) void k_e3d(const unsigned* __restrict__ sbin,
                                              const unsigned* __restrict__ gctr,
                                              const float* __restrict__ el2,
                                              const float* __restrict__ er2iv,
                                              float* __restrict__ P) {
    __shared__ float sq[CH], sEl[CH];
    int bx = blockIdx.x, c = blockIdx.y, g = blockIdx.z;
    for (int i = threadIdx.x; i < CH; i += 1024) {
        sq[i] = 0.f;
        sEl[i] = el2[(size_t)g * NN + c * CH + i];
    }
    __syncthreads();
    const float* er = er2iv + (size_t)g * NN * 2;
    const unsigned* seg = sbin + (size_t)(g * C + c) * CAP;
    unsigned size = gctr[(2 + g) * C + c];
    unsigned stride = NB1D * 1024;
    for (unsigned i = bx * 1024 + threadIdx.x; i < size; i += stride) {
        unsigned p = seg[i];
        unsigned r = p >> 16;
        float2 E = *(const float2*)(er + 2 * (size_t)(p & 0xFFFFu));
        atomicAdd(&sq[r], __expf(lrelu(sEl[r] + E.x, 0.2f)) * E.y);
    }
    __syncthreads();
    float* Pb = P + ((size_t)(g * C + c) * NB1D + bx) * CH;
    for (int i2 = threadIdx.x; i2 < CH; i2 += 1024) Pb[i2] = sq[i2];
}

// Generic partial reduce: out[idx*ostride+ooff] = (1/)sum_b P[...]
__global__ void k_red(const float* __restrict__ P, float* __restrict__ out,
                      int Cc, int NB, int CHW, int inv, int ostride, int ooff) {
    int T = 2 * Cc * CHW;
    int idx = blockIdx.x * blockDim.x + threadIdx.x;
    if (idx >= T) return;
    int gc = idx / CHW;
    int j = idx - gc * CHW;
    const float* Pp = P + ((size_t)gc * NB) * CHW + j;
    float s = 0.f;
    for (int b = 0; b < NB; ++b) s += Pp[(size_t)b * CHW];
    out[(size_t)idx * ostride + ooff] = inv ? (s != 0.f ? 1.f / s : 0.f) : s;
}

// Fused reduce(e1 partials) + node stage: facc4, el2, er2.
__global__ void k_n1r(const float* __restrict__ P, const float* __restrict__ W1,
                      const float* __restrict__ b1, const float* __restrict__ W2,
                      const float* __restrict__ al2, const float* __restrict__ ar2,
                      float* __restrict__ facc4, float* __restrict__ el2,
                      float* __restrict__ er2iv) {
    __shared__ float sW[240], sB[80], sU[80], sV[80];
    for (int t = threadIdx.x; t < 80; t += blockDim.x) {
        sW[t] = W1[t];
        sW[80 + t] = W1[160 + t];
        sW[160 + t] = W1[320 + t];
        sB[t] = b1[t];
        float u = 0.f, v = 0.f;
        for (int j = 0; j < 30; ++j) {
            float wv = W2[t * 60 + j];
            u += wv * al2[j];
            v += wv * ar2[j];
        }
        sU[t] = u;
        sV[t] = v;
    }
    __syncthreads();
    int g = blockIdx.y;
    int n = blockIdx.x * blockDim.x + threadIdx.x;
    if (n >= NN) return;
    int c = n / CH, rel = n - c * CH;
    const float* Pp = P + ((size_t)(g * C + c) * NB1D) * (CH * 4) + rel * 4;
    float4 fa = make_float4(0.f, 0.f, 0.f, 0.f);
    for (int b = 0; b < NB1D; ++b) {
        float4 p = *(const float4*)(Pp + (size_t)b * (CH * 4));
        fa.x += p.x; fa.y += p.y; fa.z += p.z; fa.w += p.w;
    }
    *(float4*)(facc4 + ((size_t)g * NN + n) * 4) = fa;
    float inv = fa.w != 0.f ? 1.f / fa.w : 0.f;
    float c0 = fa.x * inv, c1 = fa.y * inv, c2 = fa.z * inv;
    float el = 0.f, er = 0.f;
    #pragma unroll
    for (int f = 0; f < 80; ++f) {
        float gg = c0 * sW[f] + c1 * sW[80 + f] + c2 * sW[160 + f] + sB[f];
        gg = gg > 0.f ? gg : 0.f;
        el += gg * sU[f];
        er += gg * sV[f];
    }
    el2[g * NN + n] = el;
    er2iv[((size_t)g * NN + n) * 2] = er;
}

// A[g][0..79] = sum_n q[n] * g1[n]
#define RT 128
__global__ void k_r(const float* __restrict__ facc4, const float* __restrict__ W1,
                    const float* __restrict__ b1, const float* __restrict__ q,
                    float* __restrict__ A) {
    __shared__ float4 sF[RT];
    __shared__ float sQ[RT];
    __shared__ float sW[240], sB[80];
    __shared__ float sA[240];
    int t = threadIdx.x;
    for (int i = t; i < 80; i += 256) {
        sW[i] = W1[i];
        sW[80 + i] = W1[160 + i];
        sW[160 + i] = W1[320 + i];
        sB[i] = b1[i];
    }
    int g = blockIdx.y;
    int grp = t / 80, f = t - grp * 80;
    float acc = 0.f;
    for (int n0 = blockIdx.x * RT; n0 < NN; n0 += gridDim.x * RT) {
        __syncthreads();
        if (t < RT) {
            int n = n0 + t;
            sF[t] = (n < NN) ? *(const float4*)(facc4 + ((size_t)g * NN + n) * 4)
                             : make_float4(0.f, 0.f, 0.f, 0.f);
        } else if (t < 2 * RT) {
            int n = n0 + t - RT;
            sQ[t - RT] = (n < NN) ? q[g * NN + n] : 0.f;
        }
        __syncthreads();
        if (grp < 3) {
            for (int i = grp; i < RT; i += 3) {
                float qn = sQ[i];
                if (qn == 0.f) continue;
                float4 fa = sF[i];
                float inv = fa.w != 0.f ? 1.f / fa.w : 0.f;
                float c0 = fa.x * inv, c1 = fa.y * inv, c2 = fa.z * inv;
                float gg = c0 * sW[f] + c1 * sW[80 + f] + c2 * sW[160 + f] + sB[f];
                gg = gg > 0.f ? gg : 0.f;
                acc += qn * gg;
            }
        }
    }
    if (grp < 3) sA[t] = acc;
    __syncthreads();
    if (t < 80) atomicAdd(&A[g * 80 + t], sA[t] + sA[80 + t] + sA[160 + t]);
}

// Final head (+ image conv tail). 256 threads.
__global__ void k_final(const float* __restrict__ A, const float* __restrict__ W2g,
                        const float* __restrict__ b2, const float* __restrict__ Wg1,
                        const float* __restrict__ bg1, const float* __restrict__ emb_acc,
                        const float* __restrict__ Wc1, const float* __restrict__ Wc2,
                        const float* __restrict__ vocab, const float* __restrict__ W2f,
                        const float* __restrict__ W3, float* __restrict__ out, int out_size) {
    __shared__ float emb[60];
    __shared__ float hh[80 * 30];
    __shared__ float a[60];
    __shared__ float hc[70];
    __shared__ float tt[80];
    __shared__ float lp[2];
    int t = threadIdx.x;
    if (t < 60) {
        emb[t] = emb_acc[t];
        int i = t / 30, j = t % 30;
        float acc = 0.f;
        for (int f = 0; f < 80; ++f) acc += A[i * 80 + f] * W2g[f * 60 + j];
        a[t] = acc * (1.f / NN) + b2[j];
    }
    __syncthreads();
    for (int p = t; p < 2400; p += 256) {
        int i = p / 30, j = p % 30;
        float v = Wc1[i * 2 + 0] * emb[j] + Wc1[i * 2 + 1] * emb[30 + j];
        hh[p] = lrelu(v, 0.01f);
    }
    __syncthreads();
    if (t < 30) {
        float acc = 0.f;
        for (int i = 0; i < 80; ++i) acc += Wc2[i] * hh[i * 30 + t];
        hc[30 + t] = lrelu(acc, 0.01f);
        float acg = bg1[t];
        for (int j = 0; j < 60; ++j) acg += a[j] * Wg1[j * 30 + t];
        hc[t] = acg;
        if (t < 10) hc[60 + t] = vocab[t];
    }
    __syncthreads();
    if (t < 80) {
        float acc = 0.f;
        for (int qd = 0; qd < 70; ++qd) acc += hc[qd] * W2f[qd * 80 + t];
        tt[t] = acc;
    }
    __syncthreads();
    if (t < 2) {
        float acc = 0.f;
        for (int p = 0; p < 80; ++p) acc += tt[p] * W3[p * 2 + t];
        lp[t] = acc;
    }
    __syncthreads();
    if (t == 0) {
        float m = fmaxf(lp[0], lp[1]);
        float lse = m + logf(expf(lp[0] - m) + expf(lp[1] - m));
        out[0] = lp[0] - lse;
        out[1] = lp[1] - lse;
    }
    for (int i = 2 + t; i < out_size; i += blockDim.x) out[i] = 0.f;
}

extern "C" void kernel_launch(void* const* d_in, const int* in_sizes, int n_in,
                              void* d_out, int out_size, void* d_ws, size_t ws_size,
                              hipStream_t stream) {
    const float* x        = (const float*)d_in[0];
    const float* vocab    = (const float*)d_in[1];
    const float* nodef    = (const float*)d_in[2];
    const int*   src      = (const int*)d_in[3];
    const int*   dst      = (const int*)d_in[4];
    const float* W_lin1   = (const float*)d_in[5];
    const float* Wc1      = (const float*)d_in[6];
    const float* Wc2      = (const float*)d_in[7];
    const float* gat1_W   = (const float*)d_in[8];
    const float* gat1_al  = (const float*)d_in[9];
    const float* gat1_ar  = (const float*)d_in[10];
    const float* gat1_b   = (const float*)d_in[11];
    const float* gat2_W   = (const float*)d_in[12];
    const float* gat2_al  = (const float*)d_in[13];
    const float* gat2_ar  = (const float*)d_in[14];
    const float* gat2_b   = (const float*)d_in[15];
    const float* Wg1      = (const float*)d_in[16];
    const float* bg1      = (const float*)d_in[17];
    const float* W2       = (const float*)d_in[18];
    const float* W3       = (const float*)d_in[19];
    (void)in_sizes; (void)n_in; (void)ws_size;

    float* w = (float*)d_ws;
    size_t off = 0;
    auto alloc = [&](size_t n) { size_t o = off; off += (n + 63) & ~(size_t)63; return o; };
    size_t o_emb  = alloc(64);    // zeroed
    size_t o_A    = alloc(192);   // zeroed
    size_t o_ctr  = alloc(128);   // zeroed (80 u32 bin counters)
    size_t o_feat = alloc((size_t)2 * NN * 4);
    size_t o_er1  = alloc(2 * NN);
    size_t o_el2  = alloc(2 * NN);
    size_t o_eriv = alloc((size_t)2 * NN * 2);
    size_t o_facc = alloc((size_t)2 * NN * 4);
    size_t o_q    = alloc(2 * NN);
    size_t o_s16  = alloc((size_t)2 * NE / 2);
    size_t o_d16  = alloc((size_t)2 * NE / 2);
    size_t o_dbin = alloc((size_t)2 * C * CAP);
    size_t o_sbin = alloc((size_t)2 * C * CAP);
    size_t o_P    = alloc((size_t)2 * C * NB1D * CH * 4);  // 6.4M floats (max of all uses)
    u16* src16 = (u16*)(w + o_s16);
    u16* dst16 = (u16*)(w + o_d16);
    unsigned* gctr = (unsigned*)(w + o_ctr);
    unsigned* dbin = (unsigned*)(w + o_dbin);
    unsigned* sbin = (unsigned*)(w + o_sbin);

    hipMemsetAsync(w + o_emb, 0, (o_feat - o_emb) * sizeof(float), stream);
    int cvt_blocks = (2 * 2 * NE / 8 + 255) / 256;
    k_pre<<<456 + cvt_blocks, 256, 0, stream>>>(x, W_lin1, nodef, gat1_W, gat1_al, gat1_ar,
                                                src, dst, w + o_emb, w + o_feat, w + o_er1,
                                                src16, dst16);

    k_bin2<<<dim3((NE + BSL - 1) / BSL, 2, 2), 256, 0, stream>>>(dst16, src16, gctr,
                                                                 dbin, sbin);

    k_e1d<<<dim3(NB1D, C, 2), 1024, 0, stream>>>(dbin, gctr, w + o_feat, w + o_er1, w + o_P);
    k_n1r<<<dim3((NN + 255) / 256, 2), 256, 0, stream>>>(w + o_P, gat1_W, gat1_b, gat2_W,
                                                         gat2_al, gat2_ar, w + o_facc,
                                                         w + o_el2, w + o_eriv);

    k_e2d<<<dim3(NB2, C, 2), 1024, 0, stream>>>(dbin, gctr, w + o_el2, w + o_eriv, w + o_P);
    k_red<<<(2 * NN + 1023) / 1024, 1024, 0, stream>>>(w + o_P, w + o_eriv,
                                                       C, NB2, CH, 1, 2, 1);

    k_e3d<<<dim3(NB1D, C, 2), 1024, 0, stream>>>(sbin, gctr, w + o_el2, w + o_eriv, w + o_P);
    k_red<<<(2 * NN + 1023) / 1024, 1024, 0, stream>>>(w + o_P, w + o_q,
                                                       C, NB1D, CH, 0, 1, 0);

    k_r<<<dim3(128, 2), 256, 0, stream>>>(w + o_facc, gat1_W, gat1_b, w + o_q, w + o_A);
    k_final<<<1, 256, 0, stream>>>(w + o_A, gat2_W, gat2_b, Wg1, bg1, w + o_emb,
                                   Wc1, Wc2, vocab, W2, W3, (float*)d_out, out_size);
}

// Round 16
// 186.374 us; speedup vs baseline: 1.1012x; 1.1012x over previous
//
#include <hip/hip_runtime.h>
#include <math.h>

#define NN 50000
#define NE 800000

#define CH1 3125            // bin chunk: 16 chunks of 3125 nodes
#define C1  16
#define NB1D 16             // e1/e3 dense slices -> 512 blocks = 2/CU exactly
#define CH2 12500           // e2 accumulation chunk (4 dst-bins each)
#define C2  4
#define NB2 64              // e2 dense slices -> 512 blocks
#define CAP 60000           // per-bin capacity (mean 50000, sigma ~217)
#define BSL 2048            // bin edges per block

typedef unsigned short u16;

__device__ __forceinline__ float lrelu(float x, float s) { return x >= 0.f ? x : s * x; }

// Fused prologue. Blocks [0,64): image matmul. [64,456): per-node pack.
// [456,2019): u16 cvt. [2019,3583): counting-sort binning (reads int32 directly).
__global__ void k_pre(const float* __restrict__ x, const float* __restrict__ Wl,
                      const float* __restrict__ nodef,
                      const float* __restrict__ W1, const float* __restrict__ al1,
                      const float* __restrict__ ar1,
                      const int* __restrict__ src, const int* __restrict__ dst,
                      float* __restrict__ emb_acc, float* __restrict__ feat4,
                      float* __restrict__ er1, u16* __restrict__ src16,
                      u16* __restrict__ dst16, unsigned* __restrict__ gctr,
                      unsigned* __restrict__ dbin, unsigned* __restrict__ sbin) {
    int bid = blockIdx.x, t = threadIdx.x;
    if (bid < 64) {
        __shared__ float part[8][64];
        int kk = t & 31, rq = t >> 5;
        int r0 = bid * 64;
        float a0 = 0.f, a1 = 0.f;
        if (kk < 30) {
            for (int i = 0; i < 8; ++i) {
                int r = r0 + rq * 8 + i;
                float wv = Wl[r * 30 + kk];
                a0 += x[r] * wv;
                a1 += x[4096 + r] * wv;
            }
        }
        part[rq][kk] = a0;
        part[rq][32 + kk] = a1;
        __syncthreads();
        if (t < 60) {
            int g = t / 30, k = t - g * 30;
            float s = 0.f;
            #pragma unroll
            for (int rr = 0; rr < 8; ++rr) s += part[rr][g * 32 + k];
            atomicAdd(&emb_acc[g * 30 + k], s);
        }
    } else if (bid < 456) {
        __shared__ float sP[6];
        if (t < 6) {
            int c = t >> 1;
            const float* av = (t & 1) ? ar1 : al1;
            float s = 0.f;
            for (int f = 0; f < 80; ++f) s += W1[c * 160 + f] * av[f];
            sP[(t & 1) * 3 + c] = s;
        }
        __syncthreads();
        int b2 = bid - 64;
        int g = b2 / 196;
        int n = (b2 - g * 196) * 256 + t;
        if (n < NN) {
            const float* f = nodef + ((size_t)g * NN + n) * 3;
            float f0 = f[0], f1 = f[1], f2 = f[2];
            *(float4*)(feat4 + ((size_t)g * NN + n) * 4) =
                make_float4(f0, f1, f2, f0 * sP[0] + f1 * sP[1] + f2 * sP[2]);
            er1[g * NN + n] = f0 * sP[3] + f1 * sP[4] + f2 * sP[5];
        }
    } else if (bid < 2019) {
        long flat = ((long)(bid - 456) * 256 + t) * 8;
        if (flat < 2L * 2 * NE) {
            int arr = flat >= 2L * NE;
            long rem = flat - (long)arr * 2 * NE;
            int g = rem >= NE;
            int e = (int)(rem - (long)g * NE);
            const int* ip = (arr ? dst : src) + (size_t)g * NE + e;
            int4 v0 = *(const int4*)ip;
            int4 v1 = *(const int4*)(ip + 4);
            uint4 o;
            o.x = (v0.x & 0xFFFF) | (v0.y << 16);
            o.y = (v0.z & 0xFFFF) | (v0.w << 16);
            o.z = (v1.x & 0xFFFF) | (v1.y << 16);
            o.w = (v1.z & 0xFFFF) | (v1.w << 16);
            *(uint4*)((arr ? dst16 : src16) + (size_t)g * NE + e) = o;
        }
    } else {
        // counting-sort binning from int32. entry = (rel<<20)|e.
        __shared__ unsigned wcnt[4][C1];
        __shared__ unsigned wbase[4][C1];
        __shared__ unsigned wrun[4][C1];
        __shared__ unsigned sbase[C1];
        int b3 = bid - 2019;
        int a = b3 / 782;
        int rem = b3 - a * 782;
        int g = rem / 391;
        int bx = rem - g * 391;
        int wid = t >> 6;
        if (t < 64) wcnt[t >> 4][t & 15] = 0;
        __syncthreads();
        const int* ip = (a ? src : dst) + (size_t)g * NE;
        unsigned* bin = (a ? sbin : dbin);
        int cbase = (a * 2 + g) * C1;
        int bbase = g * C1;
        int e0 = bx * BSL + t * 8;
        unsigned cj[8], relj[8];
        bool act = e0 < NE;
        if (act) {
            int4 v0 = *(const int4*)(ip + e0);
            int4 v1 = *(const int4*)(ip + e0 + 4);
            int dj[8] = {v0.x, v0.y, v0.z, v0.w, v1.x, v1.y, v1.z, v1.w};
            #pragma unroll
            for (int j = 0; j < 8; ++j) {
                unsigned c = (unsigned)dj[j] / CH1;
                cj[j] = c;
                relj[j] = (unsigned)dj[j] - c * CH1;
                atomicAdd(&wcnt[wid][c], 1u);
            }
        }
        __syncthreads();
        if (t < C1) {
            unsigned s = wcnt[0][t] + wcnt[1][t] + wcnt[2][t] + wcnt[3][t];
            sbase[t] = atomicAdd(&gctr[cbase + t], s);
        }
        __syncthreads();
        if (t < 64) {
            int w2 = t >> 4, b = t & 15;
            unsigned off2 = 0;
            for (int w3 = 0; w3 < w2; ++w3) off2 += wcnt[w3][b];
            wbase[w2][b] = sbase[b] + off2;
            wrun[w2][b] = 0;
        }
        __syncthreads();
        if (act) {
            #pragma unroll
            for (int j = 0; j < 8; ++j) {
                unsigned c = cj[j];
                unsigned slot = atomicAdd(&wrun[wid][c], 1u);
                unsigned pos = wbase[wid][c] + slot;
                if (pos < CAP)
                    bin[(size_t)(bbase + c) * CAP + pos] = (relj[j] << 20) | (unsigned)(e0 + j);
            }
        }
    }
}

// Dense e1: consume dst bin. Plane-layout LDS accumulate, transpose flush.
__global__ __launch_bounds__(1024) void k_e1d(const unsigned* __restrict__ dbin,
                                              const unsigned* __restrict__ gctr,
                                              const u16* __restrict__ src16,
                                              const float* __restrict__ feat4,
                                              const float* __restrict__ er1,
                                              float* __restrict__ P) {
    __shared__ float sacc[4 * CH1];
    __shared__ float sEr[CH1];
    int bx = blockIdx.x, c = blockIdx.y, g = blockIdx.z;
    for (int i = threadIdx.x; i < 4 * CH1; i += 1024) sacc[i] = 0.f;
    int base = c * CH1;
    for (int i = threadIdx.x; i < CH1; i += 1024) sEr[i] = er1[(size_t)g * NN + base + i];
    __syncthreads();
    const u16* sp = src16 + (size_t)g * NE;
    const float* f4 = feat4 + (size_t)g * NN * 4;
    const unsigned* seg = dbin + (size_t)(g * C1 + c) * CAP;
    unsigned size = gctr[g * C1 + c];
    for (unsigned i = bx * 1024 + threadIdx.x; i < size; i += NB1D * 1024) {
        unsigned p = seg[i];
        unsigned e = p & 0xFFFFFu;
        unsigned rel = p >> 20;
        unsigned s = sp[e];
        float4 F = *(const float4*)(f4 + (size_t)s * 4);
        float wv = __expf(lrelu(F.w + sEr[rel], 0.2f));
        atomicAdd(&sacc[rel], wv * F.x);
        atomicAdd(&sacc[CH1 + rel], wv * F.y);
        atomicAdd(&sacc[2 * CH1 + rel], wv * F.z);
        atomicAdd(&sacc[3 * CH1 + rel], wv);
    }
    __syncthreads();
    float* Pb = P + ((size_t)(g * C1 + c) * NB1D + bx) * (CH1 * 4);
    for (int i = threadIdx.x; i < CH1 * 4; i += 1024)
        Pb[i] = sacc[(i & 3) * CH1 + (i >> 2)];
}

// Dense e2 (den2): 4 dst bins per CH2 chunk.
__global__ __launch_bounds__(1024) void k_e2d(const unsigned* __restrict__ dbin,
                                              const unsigned* __restrict__ gctr,
                                              const u16* __restrict__ src16,
                                              const float* __restrict__ el2,
                                              const float* __restrict__ er2iv,
                                              float* __restrict__ P) {
    __shared__ float sden[CH2];
    int bx = blockIdx.x, c2 = blockIdx.y, g = blockIdx.z;
    for (int i = threadIdx.x; i < CH2; i += 1024) sden[i] = 0.f;
    __syncthreads();
    const u16* sp = src16 + (size_t)g * NE;
    const float* el = el2 + (size_t)g * NN;
    for (int sub = 0; sub < 4; ++sub) {
        int c = c2 * 4 + sub;
        const unsigned* seg = dbin + (size_t)(g * C1 + c) * CAP;
        unsigned size = gctr[g * C1 + c];
        int roff = sub * CH1;
        const float* er = er2iv + ((size_t)g * NN + (size_t)c * CH1) * 2;
        for (unsigned i = bx * 1024 + threadIdx.x; i < size; i += NB2 * 1024) {
            unsigned p = seg[i];
            unsigned e = p & 0xFFFFFu;
            unsigned rel = p >> 20;
            float wv = __expf(lrelu(el[sp[e]] + er[2 * rel], 0.2f));
            atomicAdd(&sden[roff + rel], wv);
        }
    }
    __syncthreads();
    float* Pb = P + ((size_t)(g * C2 + c2) * NB2 + bx) * CH2;
    for (int i = threadIdx.x; i < CH2; i += 1024) Pb[i] = sden[i];
}

// Dense e3 (q): consume src bin. sq[rel] += exp(lrelu(el2[s]+er2[d])) * invden2[d].
__global__ __launch_bounds__(1024) void k_e3d(const unsigned* __restrict__ sbin,
                                              const unsigned* __restrict__ gctr,
                                              const u16* __restrict__ dst16,
                                              const float* __restrict__ el2,
                                              const float* __restrict__ er2iv,
                                              float* __restrict__ P) {
    __shared__ float sq[CH1];
    __shared__ float sEl[CH1];
    int bx = blockIdx.x, c = blockIdx.y, g = blockIdx.z;
    for (int i = threadIdx.x; i < CH1; i += 1024) {
        sq[i] = 0.f;
        sEl[i] = el2[(size_t)g * NN + c * CH1 + i];
    }
    __syncthreads();
    const u16* dp = dst16 + (size_t)g * NE;
    const float* er = er2iv + (size_t)g * NN * 2;
    const unsigned* seg = sbin + (size_t)(g * C1 + c) * CAP;
    unsigned size = gctr[(2 + g) * C1 + c];
    for (unsigned i = bx * 1024 + threadIdx.x; i < size; i += NB1D * 1024) {
        unsigned p = seg[i];
        unsigned e = p & 0xFFFFFu;
        unsigned rel = p >> 20;
        unsigned d = dp[e];
        float2 EI = *(const float2*)(er + 2 * (size_t)d);
        float wv = __expf(lrelu(sEl[rel] + EI.x, 0.2f));
        atomicAdd(&sq[rel], wv * EI.y);
    }
    __syncthreads();
    float* Pb = P + ((size_t)(g * C1 + c) * NB1D + bx) * CH1;
    for (int i = threadIdx.x; i < CH1; i += 1024) Pb[i] = sq[i];
}

// Partial reduce for den2: er2iv[2n+1] = 1/sum
__global__ void k_red(const float* __restrict__ P, float* __restrict__ out,
                      int Cc, int NB, int CHW, int inv, int ostride, int ooff) {
    int T = 2 * Cc * CHW;
    int idx = blockIdx.x * blockDim.x + threadIdx.x;
    if (idx >= T) return;
    int gc = idx / CHW;
    int j = idx - gc * CHW;
    const float* Pp = P + ((size_t)gc * NB) * CHW + j;
    float s = 0.f;
    for (int b = 0; b < NB; ++b) s += Pp[(size_t)b * CHW];
    out[(size_t)idx * ostride + ooff] = inv ? (s != 0.f ? 1.f / s : 0.f) : s;
}

// Fused reduce(e1 partials, NB1D) + node stage: facc4, el2, er2.
__global__ void k_n1r(const float* __restrict__ P, const float* __restrict__ W1,
                      const float* __restrict__ b1, const float* __restrict__ W2,
                      const float* __restrict__ al2, const float* __restrict__ ar2,
                      float* __restrict__ facc4, float* __restrict__ el2,
                      float* __restrict__ er2iv) {
    __shared__ float sW[240], sB[80], sU[80], sV[80];
    for (int t = threadIdx.x; t < 80; t += blockDim.x) {
        sW[t] = W1[t];
        sW[80 + t] = W1[160 + t];
        sW[160 + t] = W1[320 + t];
        sB[t] = b1[t];
        float u = 0.f, v = 0.f;
        for (int j = 0; j < 30; ++j) {
            float wv = W2[t * 60 + j];
            u += wv * al2[j];
            v += wv * ar2[j];
        }
        sU[t] = u;
        sV[t] = v;
    }
    __syncthreads();
    int g = blockIdx.y;
    int n = blockIdx.x * blockDim.x + threadIdx.x;
    if (n >= NN) return;
    int c = n / CH1, rel = n - c * CH1;
    const float* Pp = P + ((size_t)(g * C1 + c) * NB1D) * (CH1 * 4) + rel * 4;
    float4 fa = make_float4(0.f, 0.f, 0.f, 0.f);
    for (int b = 0; b < NB1D; ++b) {
        float4 p = *(const float4*)(Pp + (size_t)b * (CH1 * 4));
        fa.x += p.x; fa.y += p.y; fa.z += p.z; fa.w += p.w;
    }
    *(float4*)(facc4 + ((size_t)g * NN + n) * 4) = fa;
    float inv = fa.w != 0.f ? 1.f / fa.w : 0.f;
    float c0 = fa.x * inv, c1 = fa.y * inv, c2 = fa.z * inv;
    float el = 0.f, er = 0.f;
    #pragma unroll
    for (int f = 0; f < 80; ++f) {
        float gg = c0 * sW[f] + c1 * sW[80 + f] + c2 * sW[160 + f] + sB[f];
        gg = gg > 0.f ? gg : 0.f;
        el += gg * sU[f];
        er += gg * sV[f];
    }
    el2[g * NN + n] = el;
    er2iv[((size_t)g * NN + n) * 2] = er;
}

// A[g][0..79] = sum_n q[n] * g1[n], with q reduced inline from e3 partials.
#define RT 128
__global__ void k_r(const float* __restrict__ facc4, const float* __restrict__ W1,
                    const float* __restrict__ b1, const float* __restrict__ Pq,
                    float* __restrict__ A) {
    __shared__ float4 sF[RT];
    __shared__ float sQ[RT];
    __shared__ float sW[240], sB[80];
    __shared__ float sA[240];
    int t = threadIdx.x;
    for (int i = t; i < 80; i += 256) {
        sW[i] = W1[i];
        sW[80 + i] = W1[160 + i];
        sW[160 + i] = W1[320 + i];
        sB[i] = b1[i];
    }
    int g = blockIdx.y;
    int grp = t / 80, f = t - grp * 80;
    float acc = 0.f;
    for (int n0 = blockIdx.x * RT; n0 < NN; n0 += gridDim.x * RT) {
        __syncthreads();
        if (t < RT) {
            int n = n0 + t;
            sF[t] = (n < NN) ? *(const float4*)(facc4 + ((size_t)g * NN + n) * 4)
                             : make_float4(0.f, 0.f, 0.f, 0.f);
        } else if (t < 2 * RT) {
            int n = n0 + t - RT;
            float s = 0.f;
            if (n < NN) {
                int c = n / CH1, rel = n - c * CH1;
                const float* Pp = Pq + ((size_t)(g * C1 + c) * NB1D) * CH1 + rel;
                #pragma unroll
                for (int b = 0; b < NB1D; ++b) s += Pp[(size_t)b * CH1];
            }
            sQ[t - RT] = s;
        }
        __syncthreads();
        if (grp < 3) {
            for (int i = grp; i < RT; i += 3) {
                float qn = sQ[i];
                if (qn == 0.f) continue;
                float4 fa = sF[i];
                float inv = fa.w != 0.f ? 1.f / fa.w : 0.f;
                float c0 = fa.x * inv, c1 = fa.y * inv, c2 = fa.z * inv;
                float gg = c0 * sW[f] + c1 * sW[80 + f] + c2 * sW[160 + f] + sB[f];
                gg = gg > 0.f ? gg : 0.f;
                acc += qn * gg;
            }
        }
    }
    if (grp < 3) sA[t] = acc;
    __syncthreads();
    if (t < 80) atomicAdd(&A[g * 80 + t], sA[t] + sA[80 + t] + sA[160 + t]);
}

// Final head (+ image conv tail). 256 threads.
__global__ void k_final(const float* __restrict__ A, const float* __restrict__ W2g,
                        const float* __restrict__ b2, const float* __restrict__ Wg1,
                        const float* __restrict__ bg1, const float* __restrict__ emb_acc,
                        const float* __restrict__ Wc1, const float* __restrict__ Wc2,
                        const float* __restrict__ vocab, const float* __restrict__ W2f,
                        const float* __restrict__ W3, float* __restrict__ out, int out_size) {
    __shared__ float emb[60];
    __shared__ float hh[80 * 30];
    __shared__ float a[60];
    __shared__ float hc[70];
    __shared__ float tt[80];
    __shared__ float lp[2];
    int t = threadIdx.x;
    if (t < 60) {
        emb[t] = emb_acc[t];
        int i = t / 30, j = t % 30;
        float acc = 0.f;
        for (int f = 0; f < 80; ++f) acc += A[i * 80 + f] * W2g[f * 60 + j];
        a[t] = acc * (1.f / NN) + b2[j];
    }
    __syncthreads();
    for (int p = t; p < 2400; p += 256) {
        int i = p / 30, j = p % 30;
        float v = Wc1[i * 2 + 0] * emb[j] + Wc1[i * 2 + 1] * emb[30 + j];
        hh[p] = lrelu(v, 0.01f);
    }
    __syncthreads();
    if (t < 30) {
        float acc = 0.f;
        for (int i = 0; i < 80; ++i) acc += Wc2[i] * hh[i * 30 + t];
        hc[30 + t] = lrelu(acc, 0.01f);
        float acg = bg1[t];
        for (int j = 0; j < 60; ++j) acg += a[j] * Wg1[j * 30 + t];
        hc[t] = acg;
        if (t < 10) hc[60 + t] = vocab[t];
    }
    __syncthreads();
    if (t < 80) {
        float acc = 0.f;
        for (int qd = 0; qd < 70; ++qd) acc += hc[qd] * W2f[qd * 80 + t];
        tt[t] = acc;
    }
    __syncthreads();
    if (t < 2) {
        float acc = 0.f;
        for (int p = 0; p < 80; ++p) acc += tt[p] * W3[p * 2 + t];
        lp[t] = acc;
    }
    __syncthreads();
    if (t == 0) {
        float m = fmaxf(lp[0], lp[1]);
        float lse = m + logf(expf(lp[0] - m) + expf(lp[1] - m));
        out[0] = lp[0] - lse;
        out[1] = lp[1] - lse;
    }
    for (int i = 2 + t; i < out_size; i += blockDim.x) out[i] = 0.f;
}

extern "C" void kernel_launch(void* const* d_in, const int* in_sizes, int n_in,
                              void* d_out, int out_size, void* d_ws, size_t ws_size,
                              hipStream_t stream) {
    const float* x        = (const float*)d_in[0];
    const float* vocab    = (const float*)d_in[1];
    const float* nodef    = (const float*)d_in[2];
    const int*   src      = (const int*)d_in[3];
    const int*   dst      = (const int*)d_in[4];
    const float* W_lin1   = (const float*)d_in[5];
    const float* Wc1      = (const float*)d_in[6];
    const float* Wc2      = (const float*)d_in[7];
    const float* gat1_W   = (const float*)d_in[8];
    const float* gat1_al  = (const float*)d_in[9];
    const float* gat1_ar  = (const float*)d_in[10];
    const float* gat1_b   = (const float*)d_in[11];
    const float* gat2_W   = (const float*)d_in[12];
    const float* gat2_al  = (const float*)d_in[13];
    const float* gat2_ar  = (const float*)d_in[14];
    const float* gat2_b   = (const float*)d_in[15];
    const float* Wg1      = (const float*)d_in[16];
    const float* bg1      = (const float*)d_in[17];
    const float* W2       = (const float*)d_in[18];
    const float* W3       = (const float*)d_in[19];
    (void)in_sizes; (void)n_in; (void)ws_size;

    float* w = (float*)d_ws;
    size_t off = 0;
    auto alloc = [&](size_t n) { size_t o = off; off += (n + 63) & ~(size_t)63; return o; };
    size_t o_emb  = alloc(64);    // zeroed
    size_t o_A    = alloc(192);   // zeroed
    size_t o_ctr  = alloc(128);   // zeroed (64 u32 bin counters)
    size_t o_feat = alloc((size_t)2 * NN * 4);
    size_t o_er1  = alloc(2 * NN);
    size_t o_el2  = alloc(2 * NN);
    size_t o_eriv = alloc((size_t)2 * NN * 2);
    size_t o_facc = alloc((size_t)2 * NN * 4);
    size_t o_s16  = alloc((size_t)2 * NE / 2);
    size_t o_d16  = alloc((size_t)2 * NE / 2);
    size_t o_dbin = alloc((size_t)2 * C1 * CAP);
    size_t o_sbin = alloc((size_t)2 * C1 * CAP);
    size_t o_P    = alloc((size_t)2 * C1 * NB1D * CH1 * 4);  // 6.4M floats (max use)
    u16* src16 = (u16*)(w + o_s16);
    u16* dst16 = (u16*)(w + o_d16);
    unsigned* gctr = (unsigned*)(w + o_ctr);
    unsigned* dbin = (unsigned*)(w + o_dbin);
    unsigned* sbin = (unsigned*)(w + o_sbin);

    hipMemsetAsync(w + o_emb, 0, (o_feat - o_emb) * sizeof(float), stream);
    // grid: 64 img + 392 pack + 1563 cvt + 1564 bin = 3583
    k_pre<<<3583, 256, 0, stream>>>(x, W_lin1, nodef, gat1_W, gat1_al, gat1_ar,
                                    src, dst, w + o_emb, w + o_feat, w + o_er1,
                                    src16, dst16, gctr, dbin, sbin);

    k_e1d<<<dim3(NB1D, C1, 2), 1024, 0, stream>>>(dbin, gctr, src16, w + o_feat,
                                                  w + o_er1, w + o_P);
    k_n1r<<<dim3((NN + 255) / 256, 2), 256, 0, stream>>>(w + o_P, gat1_W, gat1_b, gat2_W,
                                                         gat2_al, gat2_ar, w + o_facc,
                                                         w + o_el2, w + o_eriv);

    k_e2d<<<dim3(NB2, C2, 2), 1024, 0, stream>>>(dbin, gctr, src16, w + o_el2,
                                                 w + o_eriv, w + o_P);
    k_red<<<(2 * NN + 1023) / 1024, 1024, 0, stream>>>(w + o_P, w + o_eriv,
                                                       C2, NB2, CH2, 1, 2, 1);

    k_e3d<<<dim3(NB1D, C1, 2), 1024, 0, stream>>>(sbin, gctr, dst16, w + o_el2,
                                                  w + o_eriv, w + o_P);

    k_r<<<dim3(128, 2), 256, 0, stream>>>(w + o_facc, gat1_W, gat1_b, w + o_P, w + o_A);
    k_final<<<1, 256, 0, stream>>>(w + o_A, gat2_W, gat2_b, Wg1, bg1, w + o_emb,
                                   Wc1, Wc2, vocab, W2, W3, (float*)d_out, out_size);
}

// Round 17
// 144.544 us; speedup vs baseline: 1.4199x; 1.2894x over previous
//
#include <hip/hip_runtime.h>
#include <math.h>

#define NN 50000
#define NE 800000

#define CH 196              // nodes per chunk
#define C  256              // chunks (256*196 = 50176 >= NN); one block owns one chunk
#define CAP 3600            // per-bin capacity (mean 3125, sigma ~56)
#define BSL 2048            // bin edges per block

__device__ __forceinline__ float lrelu(float x, float s) { return x >= 0.f ? x : s * x; }

// Fused prologue. Blocks [0,64): image matmul. [64,456): per-node pack.
// [456,2020): counting-sort binning from int32; entry = (rel<<16)|partner.
__global__ void k_pre(const float* __restrict__ x, const float* __restrict__ Wl,
                      const float* __restrict__ nodef,
                      const float* __restrict__ W1, const float* __restrict__ al1,
                      const float* __restrict__ ar1,
                      const int* __restrict__ src, const int* __restrict__ dst,
                      float* __restrict__ emb_acc, float* __restrict__ feat4,
                      float* __restrict__ er1, unsigned* __restrict__ gctr,
                      unsigned* __restrict__ dbin, unsigned* __restrict__ sbin) {
    int bid = blockIdx.x, t = threadIdx.x;
    if (bid < 64) {
        __shared__ float part[8][64];
        int kk = t & 31, rq = t >> 5;
        int r0 = bid * 64;
        float a0 = 0.f, a1 = 0.f;
        if (kk < 30) {
            for (int i = 0; i < 8; ++i) {
                int r = r0 + rq * 8 + i;
                float wv = Wl[r * 30 + kk];
                a0 += x[r] * wv;
                a1 += x[4096 + r] * wv;
            }
        }
        part[rq][kk] = a0;
        part[rq][32 + kk] = a1;
        __syncthreads();
        if (t < 60) {
            int g = t / 30, k = t - g * 30;
            float s = 0.f;
            #pragma unroll
            for (int rr = 0; rr < 8; ++rr) s += part[rr][g * 32 + k];
            atomicAdd(&emb_acc[g * 30 + k], s);
        }
    } else if (bid < 456) {
        __shared__ float sP[6];
        if (t < 6) {
            int c = t >> 1;
            const float* av = (t & 1) ? ar1 : al1;
            float s = 0.f;
            for (int f = 0; f < 80; ++f) s += W1[c * 160 + f] * av[f];
            sP[(t & 1) * 3 + c] = s;
        }
        __syncthreads();
        int b2 = bid - 64;
        int g = b2 / 196;
        int n = (b2 - g * 196) * 256 + t;
        if (n < NN) {
            const float* f = nodef + ((size_t)g * NN + n) * 3;
            float f0 = f[0], f1 = f[1], f2 = f[2];
            *(float4*)(feat4 + ((size_t)g * NN + n) * 4) =
                make_float4(f0, f1, f2, f0 * sP[0] + f1 * sP[1] + f2 * sP[2]);
            er1[g * NN + n] = f0 * sP[3] + f1 * sP[4] + f2 * sP[5];
        }
    } else {
        __shared__ unsigned wcnt[4][C];
        __shared__ unsigned wbase[4][C];
        __shared__ unsigned wrun[4][C];
        __shared__ unsigned sbase2[C];
        int b3 = bid - 456;
        int a = b3 / 782;
        int rem2 = b3 - a * 782;
        int g = rem2 / 391;
        int bx = rem2 - g * 391;
        int wid = t >> 6;
        for (int i = t; i < 4 * C; i += 256) ((unsigned*)wcnt)[i] = 0;
        __syncthreads();
        const int* ip = (a ? src : dst) + (size_t)g * NE;
        const int* pp = (a ? dst : src) + (size_t)g * NE;
        unsigned* bin = (a ? sbin : dbin);
        int cbase = (a * 2 + g) * C;
        int bbase = g * C;
        int e0 = bx * BSL + t * 8;
        int nv = 0;
        if (e0 < NE) nv = (NE - e0) < 8 ? (NE - e0) : 8;
        unsigned cj[8], pk[8];
        if (nv == 8) {
            int4 v0 = *(const int4*)(ip + e0), v1 = *(const int4*)(ip + e0 + 4);
            int4 q0 = *(const int4*)(pp + e0), q1 = *(const int4*)(pp + e0 + 4);
            int dj[8] = {v0.x, v0.y, v0.z, v0.w, v1.x, v1.y, v1.z, v1.w};
            int pj[8] = {q0.x, q0.y, q0.z, q0.w, q1.x, q1.y, q1.z, q1.w};
            #pragma unroll
            for (int j = 0; j < 8; ++j) {
                unsigned c = (unsigned)dj[j] / CH;
                cj[j] = c;
                pk[j] = (((unsigned)dj[j] - c * CH) << 16) | (unsigned)pj[j];
                atomicAdd(&wcnt[wid][c], 1u);
            }
        } else {
            for (int j = 0; j < nv; ++j) {
                int dv = ip[e0 + j], pv = pp[e0 + j];
                unsigned c = (unsigned)dv / CH;
                cj[j] = c;
                pk[j] = (((unsigned)dv - c * CH) << 16) | (unsigned)pv;
                atomicAdd(&wcnt[wid][c], 1u);
            }
        }
        __syncthreads();
        if (t < C) {
            unsigned s = wcnt[0][t] + wcnt[1][t] + wcnt[2][t] + wcnt[3][t];
            sbase2[t] = atomicAdd(&gctr[cbase + t], s);
        }
        __syncthreads();
        for (int i = t; i < 4 * C; i += 256) {
            int w2 = i / C, b = i - w2 * C;
            unsigned off2 = 0;
            for (int w3 = 0; w3 < w2; ++w3) off2 += wcnt[w3][b];
            wbase[w2][b] = sbase2[b] + off2;
            wrun[w2][b] = 0;
        }
        __syncthreads();
        for (int j = 0; j < nv; ++j) {
            unsigned c = cj[j];
            unsigned slot = atomicAdd(&wrun[wid][c], 1u);
            unsigned pos = wbase[wid][c] + slot;
            if (pos < CAP) bin[(size_t)(bbase + c) * CAP + pos] = pk[j];
        }
    }
}

// e1 + node stage fused. One block per (chunk, graph); writes facc4/el2/er2 directly.
__global__ __launch_bounds__(1024) void k_e1n(const unsigned* __restrict__ dbin,
                                              const unsigned* __restrict__ gctr,
                                              const float* __restrict__ feat4,
                                              const float* __restrict__ er1,
                                              const float* __restrict__ W1,
                                              const float* __restrict__ b1,
                                              const float* __restrict__ W2,
                                              const float* __restrict__ al2,
                                              const float* __restrict__ ar2,
                                              float* __restrict__ facc4,
                                              float* __restrict__ el2,
                                              float* __restrict__ er2iv) {
    __shared__ float sacc[4 * CH];
    __shared__ float sEr[CH];
    __shared__ float sW[240], sB[80], sU[80], sV[80];
    int c = blockIdx.x, g = blockIdx.y, t = threadIdx.x;
    int base = c * CH;
    for (int i = t; i < 4 * CH; i += 1024) sacc[i] = 0.f;
    if (t < CH) sEr[t] = (base + t < NN) ? er1[(size_t)g * NN + base + t] : 0.f;
    if (t >= 1024 - 80) {  // distinct wave does weight prep
        int f = t - (1024 - 80);
        sW[f] = W1[f];
        sW[80 + f] = W1[160 + f];
        sW[160 + f] = W1[320 + f];
        sB[f] = b1[f];
        float u = 0.f, v = 0.f;
        for (int j = 0; j < 30; ++j) {
            float wv = W2[f * 60 + j];
            u += wv * al2[j];
            v += wv * ar2[j];
        }
        sU[f] = u;
        sV[f] = v;
    }
    __syncthreads();
    const float* f4 = feat4 + (size_t)g * NN * 4;
    const unsigned* seg = dbin + (size_t)(g * C + c) * CAP;
    unsigned size = gctr[g * C + c];
    for (unsigned i = t; i < size; i += 1024) {
        unsigned p = seg[i];
        unsigned s = p & 0xFFFFu;
        unsigned rel = p >> 16;
        float4 F = *(const float4*)(f4 + (size_t)s * 4);
        float wv = __expf(lrelu(F.w + sEr[rel], 0.2f));
        atomicAdd(&sacc[rel], wv * F.x);
        atomicAdd(&sacc[CH + rel], wv * F.y);
        atomicAdd(&sacc[2 * CH + rel], wv * F.z);
        atomicAdd(&sacc[3 * CH + rel], wv);
    }
    __syncthreads();
    if (t < CH && base + t < NN) {
        size_t n = (size_t)g * NN + base + t;
        float fx = sacc[t], fy = sacc[CH + t], fz = sacc[2 * CH + t], fw = sacc[3 * CH + t];
        *(float4*)(facc4 + n * 4) = make_float4(fx, fy, fz, fw);
        float inv = fw != 0.f ? 1.f / fw : 0.f;
        float c0 = fx * inv, c1 = fy * inv, c2 = fz * inv;
        float el = 0.f, er = 0.f;
        #pragma unroll
        for (int f = 0; f < 80; ++f) {
            float gg = c0 * sW[f] + c1 * sW[80 + f] + c2 * sW[160 + f] + sB[f];
            gg = gg > 0.f ? gg : 0.f;
            el += gg * sU[f];
            er += gg * sV[f];
        }
        el2[n] = el;
        er2iv[n * 2] = er;
    }
}

// e2 (den2): one block per chunk; entry = (rel<<16)|src. Writes invden in-place.
__global__ __launch_bounds__(1024) void k_e2d(const unsigned* __restrict__ dbin,
                                              const unsigned* __restrict__ gctr,
                                              const float* __restrict__ el2,
                                              float* __restrict__ er2iv) {
    __shared__ float sden[CH], sEr2[CH];
    int c = blockIdx.x, g = blockIdx.y, t = threadIdx.x;
    int base = c * CH;
    if (t < CH) {
        sden[t] = 0.f;
        sEr2[t] = (base + t < NN) ? er2iv[((size_t)g * NN + base + t) * 2] : 0.f;
    }
    __syncthreads();
    const float* el = el2 + (size_t)g * NN;
    const unsigned* seg = dbin + (size_t)(g * C + c) * CAP;
    unsigned size = gctr[g * C + c];
    for (unsigned i = t; i < size; i += 1024) {
        unsigned p = seg[i];
        unsigned rel = p >> 16;
        atomicAdd(&sden[rel], __expf(lrelu(el[p & 0xFFFFu] + sEr2[rel], 0.2f)));
    }
    __syncthreads();
    if (t < CH && base + t < NN) {
        float s = sden[t];
        er2iv[((size_t)g * NN + base + t) * 2 + 1] = s != 0.f ? 1.f / s : 0.f;
    }
}

// e3 (q): one block per src-chunk; entry = (rel<<16)|dst. Writes q directly.
__global__ __launch_bounds__(1024) void k_e3d(const unsigned* __restrict__ sbin,
                                              const unsigned* __restrict__ gctr,
                                              const float* __restrict__ el2,
                                              const float* __restrict__ er2iv,
                                              float* __restrict__ q) {
    __shared__ float sq[CH], sEl[CH];
    int c = blockIdx.x, g = blockIdx.y, t = threadIdx.x;
    int base = c * CH;
    if (t < CH) {
        sq[t] = 0.f;
        sEl[t] = (base + t < NN) ? el2[(size_t)g * NN + base + t] : 0.f;
    }
    __syncthreads();
    const float* er = er2iv + (size_t)g * NN * 2;
    const unsigned* seg = sbin + (size_t)(g * C + c) * CAP;
    unsigned size = gctr[(2 + g) * C + c];
    for (unsigned i = t; i < size; i += 1024) {
        unsigned p = seg[i];
        unsigned rel = p >> 16;
        float2 E = *(const float2*)(er + 2 * (size_t)(p & 0xFFFFu));
        atomicAdd(&sq[rel], __expf(lrelu(sEl[rel] + E.x, 0.2f)) * E.y);
    }
    __syncthreads();
    if (t < CH && base + t < NN) q[g * NN + base + t] = sq[t];
}

// A[g][0..79] = sum_n q[n] * g1[n]
#define RT 128
__global__ void k_r(const float* __restrict__ facc4, const float* __restrict__ W1,
                    const float* __restrict__ b1, const float* __restrict__ q,
                    float* __restrict__ A) {
    __shared__ float4 sF[RT];
    __shared__ float sQ[RT];
    __shared__ float sW[240], sB[80];
    __shared__ float sA[240];
    int t = threadIdx.x;
    for (int i = t; i < 80; i += 256) {
        sW[i] = W1[i];
        sW[80 + i] = W1[160 + i];
        sW[160 + i] = W1[320 + i];
        sB[i] = b1[i];
    }
    int g = blockIdx.y;
    int grp = t / 80, f = t - grp * 80;
    float acc = 0.f;
    for (int n0 = blockIdx.x * RT; n0 < NN; n0 += gridDim.x * RT) {
        __syncthreads();
        if (t < RT) {
            int n = n0 + t;
            sF[t] = (n < NN) ? *(const float4*)(facc4 + ((size_t)g * NN + n) * 4)
                             : make_float4(0.f, 0.f, 0.f, 0.f);
        } else if (t < 2 * RT) {
            int n = n0 + t - RT;
            sQ[t - RT] = (n < NN) ? q[g * NN + n] : 0.f;
        }
        __syncthreads();
        if (grp < 3) {
            for (int i = grp; i < RT; i += 3) {
                float qn = sQ[i];
                if (qn == 0.f) continue;
                float4 fa = sF[i];
                float inv = fa.w != 0.f ? 1.f / fa.w : 0.f;
                float c0 = fa.x * inv, c1 = fa.y * inv, c2 = fa.z * inv;
                float gg = c0 * sW[f] + c1 * sW[80 + f] + c2 * sW[160 + f] + sB[f];
                gg = gg > 0.f ? gg : 0.f;
                acc += qn * gg;
            }
        }
    }
    if (grp < 3) sA[t] = acc;
    __syncthreads();
    if (t < 80) atomicAdd(&A[g * 80 + t], sA[t] + sA[80 + t] + sA[160 + t]);
}

// Final head (+ image conv tail). 256 threads.
__global__ void k_final(const float* __restrict__ A, const float* __restrict__ W2g,
                        const float* __restrict__ b2, const float* __restrict__ Wg1,
                        const float* __restrict__ bg1, const float* __restrict__ emb_acc,
                        const float* __restrict__ Wc1, const float* __restrict__ Wc2,
                        const float* __restrict__ vocab, const float* __restrict__ W2f,
                        const float* __restrict__ W3, float* __restrict__ out, int out_size) {
    __shared__ float emb[60];
    __shared__ float hh[80 * 30];
    __shared__ float a[60];
    __shared__ float hc[70];
    __shared__ float tt[80];
    __shared__ float lp[2];
    int t = threadIdx.x;
    if (t < 60) {
        emb[t] = emb_acc[t];
        int i = t / 30, j = t % 30;
        float acc = 0.f;
        for (int f = 0; f < 80; ++f) acc += A[i * 80 + f] * W2g[f * 60 + j];
        a[t] = acc * (1.f / NN) + b2[j];
    }
    __syncthreads();
    for (int p = t; p < 2400; p += 256) {
        int i = p / 30, j = p % 30;
        float v = Wc1[i * 2 + 0] * emb[j] + Wc1[i * 2 + 1] * emb[30 + j];
        hh[p] = lrelu(v, 0.01f);
    }
    __syncthreads();
    if (t < 30) {
        float acc = 0.f;
        for (int i = 0; i < 80; ++i) acc += Wc2[i] * hh[i * 30 + t];
        hc[30 + t] = lrelu(acc, 0.01f);
        float acg = bg1[t];
        for (int j = 0; j < 60; ++j) acg += a[j] * Wg1[j * 30 + t];
        hc[t] = acg;
        if (t < 10) hc[60 + t] = vocab[t];
    }
    __syncthreads();
    if (t < 80) {
        float acc = 0.f;
        for (int qd = 0; qd < 70; ++qd) acc += hc[qd] * W2f[qd * 80 + t];
        tt[t] = acc;
    }
    __syncthreads();
    if (t < 2) {
        float acc = 0.f;
        for (int p = 0; p < 80; ++p) acc += tt[p] * W3[p * 2 + t];
        lp[t] = acc;
    }
    __syncthreads();
    if (t == 0) {
        float m = fmaxf(lp[0], lp[1]);
        float lse = m + logf(expf(lp[0] - m) + expf(lp[1] - m));
        out[0] = lp[0] - lse;
        out[1] = lp[1] - lse;
    }
    for (int i = 2 + t; i < out_size; i += blockDim.x) out[i] = 0.f;
}

extern "C" void kernel_launch(void* const* d_in, const int* in_sizes, int n_in,
                              void* d_out, int out_size, void* d_ws, size_t ws_size,
                              hipStream_t stream) {
    const float* x        = (const float*)d_in[0];
    const float* vocab    = (const float*)d_in[1];
    const float* nodef    = (const float*)d_in[2];
    const int*   src      = (const int*)d_in[3];
    const int*   dst      = (const int*)d_in[4];
    const float* W_lin1   = (const float*)d_in[5];
    const float* Wc1      = (const float*)d_in[6];
    const float* Wc2      = (const float*)d_in[7];
    const float* gat1_W   = (const float*)d_in[8];
    const float* gat1_al  = (const float*)d_in[9];
    const float* gat1_ar  = (const float*)d_in[10];
    const float* gat1_b   = (const float*)d_in[11];
    const float* gat2_W   = (const float*)d_in[12];
    const float* gat2_al  = (const float*)d_in[13];
    const float* gat2_ar  = (const float*)d_in[14];
    const float* gat2_b   = (const float*)d_in[15];
    const float* Wg1      = (const float*)d_in[16];
    const float* bg1      = (const float*)d_in[17];
    const float* W2       = (const float*)d_in[18];
    const float* W3       = (const float*)d_in[19];
    (void)in_sizes; (void)n_in; (void)ws_size;

    float* w = (float*)d_ws;
    size_t off = 0;
    auto alloc = [&](size_t n) { size_t o = off; off += (n + 63) & ~(size_t)63; return o; };
    size_t o_emb  = alloc(64);    // zeroed
    size_t o_A    = alloc(192);   // zeroed
    size_t o_ctr  = alloc(1024);  // zeroed (4*C u32 bin counters)
    size_t o_feat = alloc((size_t)2 * NN * 4);
    size_t o_er1  = alloc(2 * NN);
    size_t o_el2  = alloc(2 * NN);
    size_t o_eriv = alloc((size_t)2 * NN * 2);
    size_t o_facc = alloc((size_t)2 * NN * 4);
    size_t o_q    = alloc(2 * NN);
    size_t o_dbin = alloc((size_t)2 * C * CAP);
    size_t o_sbin = alloc((size_t)2 * C * CAP);
    unsigned* gctr = (unsigned*)(w + o_ctr);
    unsigned* dbin = (unsigned*)(w + o_dbin);
    unsigned* sbin = (unsigned*)(w + o_sbin);

    hipMemsetAsync(w + o_emb, 0, (o_feat - o_emb) * sizeof(float), stream);
    // grid: 64 img + 392 pack + 1564 bin = 2020
    k_pre<<<2020, 256, 0, stream>>>(x, W_lin1, nodef, gat1_W, gat1_al, gat1_ar,
                                    src, dst, w + o_emb, w + o_feat, w + o_er1,
                                    gctr, dbin, sbin);

    k_e1n<<<dim3(C, 2), 1024, 0, stream>>>(dbin, gctr, w + o_feat, w + o_er1,
                                           gat1_W, gat1_b, gat2_W, gat2_al, gat2_ar,
                                           w + o_facc, w + o_el2, w + o_eriv);

    k_e2d<<<dim3(C, 2), 1024, 0, stream>>>(dbin, gctr, w + o_el2, w + o_eriv);

    k_e3d<<<dim3(C, 2), 1024, 0, stream>>>(sbin, gctr, w + o_el2, w + o_eriv, w + o_q);

    k_r<<<dim3(128, 2), 256, 0, stream>>>(w + o_facc, gat1_W, gat1_b, w + o_q, w + o_A);
    k_final<<<1, 256, 0, stream>>>(w + o_A, gat2_W, gat2_b, Wg1, bg1, w + o_emb,
                                   Wc1, Wc2, vocab, W2, W3, (float*)d_out, out_size);
}

// Round 18
// 125.882 us; speedup vs baseline: 1.6304x; 1.1482x over previous
//
#include <hip/hip_runtime.h>
#include <math.h>

#define NN 50000
#define NE 800000

#define CH 196              // nodes per chunk
#define C  256              // chunks (256*196 = 50176 >= NN); one block owns one chunk
#define CAP 3600            // per-bin capacity (mean 3125, sigma ~56)
#define BSL 2048            // bin edges per block

__device__ __forceinline__ float lrelu(float x, float s) { return x >= 0.f ? x : s * x; }

// Fused prologue. Blocks [0,64): image matmul. [64,456): per-node pack.
// [456,2020): counting-sort binning from int32; entry = (rel<<16)|partner.
__global__ void k_pre(const float* __restrict__ x, const float* __restrict__ Wl,
                      const float* __restrict__ nodef,
                      const float* __restrict__ W1, const float* __restrict__ al1,
                      const float* __restrict__ ar1,
                      const int* __restrict__ src, const int* __restrict__ dst,
                      float* __restrict__ emb_acc, float* __restrict__ feat4,
                      float* __restrict__ er1, unsigned* __restrict__ gctr,
                      unsigned* __restrict__ dbin, unsigned* __restrict__ sbin) {
    int bid = blockIdx.x, t = threadIdx.x;
    if (bid < 64) {
        __shared__ float part[8][64];
        int kk = t & 31, rq = t >> 5;
        int r0 = bid * 64;
        float a0 = 0.f, a1 = 0.f;
        if (kk < 30) {
            for (int i = 0; i < 8; ++i) {
                int r = r0 + rq * 8 + i;
                float wv = Wl[r * 30 + kk];
                a0 += x[r] * wv;
                a1 += x[4096 + r] * wv;
            }
        }
        part[rq][kk] = a0;
        part[rq][32 + kk] = a1;
        __syncthreads();
        if (t < 60) {
            int g = t / 30, k = t - g * 30;
            float s = 0.f;
            #pragma unroll
            for (int rr = 0; rr < 8; ++rr) s += part[rr][g * 32 + k];
            atomicAdd(&emb_acc[g * 30 + k], s);
        }
    } else if (bid < 456) {
        __shared__ float sP[6];
        if (t < 6) {
            int c = t >> 1;
            const float* av = (t & 1) ? ar1 : al1;
            float s = 0.f;
            for (int f = 0; f < 80; ++f) s += W1[c * 160 + f] * av[f];
            sP[(t & 1) * 3 + c] = s;
        }
        __syncthreads();
        int b2 = bid - 64;
        int g = b2 / 196;
        int n = (b2 - g * 196) * 256 + t;
        if (n < NN) {
            const float* f = nodef + ((size_t)g * NN + n) * 3;
            float f0 = f[0], f1 = f[1], f2 = f[2];
            *(float4*)(feat4 + ((size_t)g * NN + n) * 4) =
                make_float4(f0, f1, f2, f0 * sP[0] + f1 * sP[1] + f2 * sP[2]);
            er1[g * NN + n] = f0 * sP[3] + f1 * sP[4] + f2 * sP[5];
        }
    } else {
        __shared__ unsigned wcnt[4][C];
        __shared__ unsigned wbase[4][C];
        __shared__ unsigned wrun[4][C];
        __shared__ unsigned sbase2[C];
        int b3 = bid - 456;
        int a = b3 / 782;
        int rem2 = b3 - a * 782;
        int g = rem2 / 391;
        int bx = rem2 - g * 391;
        int wid = t >> 6;
        for (int i = t; i < 4 * C; i += 256) ((unsigned*)wcnt)[i] = 0;
        __syncthreads();
        const int* ip = (a ? src : dst) + (size_t)g * NE;
        const int* pp = (a ? dst : src) + (size_t)g * NE;
        unsigned* bin = (a ? sbin : dbin);
        int cbase = (a * 2 + g) * C;
        int bbase = g * C;
        int e0 = bx * BSL + t * 8;
        int nv = 0;
        if (e0 < NE) nv = (NE - e0) < 8 ? (NE - e0) : 8;
        unsigned cj[8], pk[8];
        if (nv == 8) {
            int4 v0 = *(const int4*)(ip + e0), v1 = *(const int4*)(ip + e0 + 4);
            int4 q0 = *(const int4*)(pp + e0), q1 = *(const int4*)(pp + e0 + 4);
            int dj[8] = {v0.x, v0.y, v0.z, v0.w, v1.x, v1.y, v1.z, v1.w};
            int pj[8] = {q0.x, q0.y, q0.z, q0.w, q1.x, q1.y, q1.z, q1.w};
            #pragma unroll
            for (int j = 0; j < 8; ++j) {
                unsigned c = (unsigned)dj[j] / CH;
                cj[j] = c;
                pk[j] = (((unsigned)dj[j] - c * CH) << 16) | (unsigned)pj[j];
                atomicAdd(&wcnt[wid][c], 1u);
            }
        } else {
            for (int j = 0; j < nv; ++j) {
                int dv = ip[e0 + j], pv = pp[e0 + j];
                unsigned c = (unsigned)dv / CH;
                cj[j] = c;
                pk[j] = (((unsigned)dv - c * CH) << 16) | (unsigned)pv;
                atomicAdd(&wcnt[wid][c], 1u);
            }
        }
        __syncthreads();
        if (t < C) {
            unsigned s = wcnt[0][t] + wcnt[1][t] + wcnt[2][t] + wcnt[3][t];
            sbase2[t] = atomicAdd(&gctr[cbase + t], s);
        }
        __syncthreads();
        for (int i = t; i < 4 * C; i += 256) {
            int w2 = i / C, b = i - w2 * C;
            unsigned off2 = 0;
            for (int w3 = 0; w3 < w2; ++w3) off2 += wcnt[w3][b];
            wbase[w2][b] = sbase2[b] + off2;
            wrun[w2][b] = 0;
        }
        __syncthreads();
        for (int j = 0; j < nv; ++j) {
            unsigned c = cj[j];
            unsigned slot = atomicAdd(&wrun[wid][c], 1u);
            unsigned pos = wbase[wid][c] + slot;
            if (pos < CAP) bin[(size_t)(bbase + c) * CAP + pos] = pk[j];
        }
    }
}

// e1 + node stage, via in-LDS counting sort + register accumulation (no float LDS atomics).
__global__ __launch_bounds__(1024) void k_e1n(const unsigned* __restrict__ dbin,
                                              const unsigned* __restrict__ gctr,
                                              const float* __restrict__ feat4,
                                              const float* __restrict__ er1,
                                              const float* __restrict__ W1,
                                              const float* __restrict__ b1,
                                              const float* __restrict__ W2,
                                              const float* __restrict__ al2,
                                              const float* __restrict__ ar2,
                                              float* __restrict__ facc4,
                                              float* __restrict__ el2,
                                              float* __restrict__ er2iv) {
    __shared__ unsigned scnt[CH];
    __shared__ unsigned sstart[CH + 1];
    __shared__ unsigned sofs[CH];
    __shared__ unsigned ssort[CAP];
    __shared__ float sEr[CH];
    __shared__ float pacc[8][CH];   // [half*4+comp][rel]
    __shared__ float sW[240], sB[80], sU[80], sV[80];
    int c = blockIdx.x, g = blockIdx.y, t = threadIdx.x;
    int base = c * CH;
    if (t < CH) {
        scnt[t] = 0;
        sEr[t] = (base + t < NN) ? er1[(size_t)g * NN + base + t] : 0.f;
    }
    if (t >= 1024 - 80) {  // distinct wave does weight prep
        int f = t - (1024 - 80);
        sW[f] = W1[f];
        sW[80 + f] = W1[160 + f];
        sW[160 + f] = W1[320 + f];
        sB[f] = b1[f];
        float u = 0.f, v = 0.f;
        for (int j = 0; j < 30; ++j) {
            float wv = W2[f * 60 + j];
            u += wv * al2[j];
            v += wv * ar2[j];
        }
        sU[f] = u;
        sV[f] = v;
    }
    __syncthreads();
    const unsigned* seg = dbin + (size_t)(g * C + c) * CAP;
    unsigned size = gctr[g * C + c];
    if (size > CAP) size = CAP;
    // Phase A: histogram by rel (1 u32 LDS atomic per entry)
    for (unsigned i = t; i < size; i += 1024) atomicAdd(&scnt[seg[i] >> 16], 1u);
    __syncthreads();
    // Phase B: exclusive prefix
    if (t == 0) {
        unsigned run = 0;
        for (int j = 0; j < CH; ++j) { sstart[j] = run; run += scnt[j]; }
        sstart[CH] = run;
    }
    __syncthreads();
    if (t < CH) sofs[t] = sstart[t];
    __syncthreads();
    // Phase C: scatter into sorted order (1 u32 LDS atomic per entry)
    for (unsigned i = t; i < size; i += 1024) {
        unsigned p = seg[i];
        unsigned slot = atomicAdd(&sofs[p >> 16], 1u);
        ssort[slot] = p & 0xFFFFu;
    }
    __syncthreads();
    // Phase D: 2 threads per node, register accumulation over contiguous segment
    const float* f4 = feat4 + (size_t)g * NN * 4;
    if (t < 2 * CH) {
        int rel = t >> 1, half = t & 1;
        unsigned start = sstart[rel], end = sstart[rel + 1];
        unsigned mid = (start + end) >> 1;
        unsigned lo = half ? mid : start;
        unsigned hi = half ? end : mid;
        float ax = 0.f, ay = 0.f, az = 0.f, aw = 0.f;
        float erv = sEr[rel];
        for (unsigned j = lo; j < hi; ++j) {
            unsigned s = ssort[j];
            float4 F = *(const float4*)(f4 + (size_t)s * 4);
            float wv = __expf(lrelu(F.w + erv, 0.2f));
            ax += wv * F.x; ay += wv * F.y; az += wv * F.z; aw += wv;
        }
        int hb = half * 4;
        pacc[hb + 0][rel] = ax;
        pacc[hb + 1][rel] = ay;
        pacc[hb + 2][rel] = az;
        pacc[hb + 3][rel] = aw;
    }
    __syncthreads();
    if (t < CH && base + t < NN) {
        size_t n = (size_t)g * NN + base + t;
        float fx = pacc[0][t] + pacc[4][t];
        float fy = pacc[1][t] + pacc[5][t];
        float fz = pacc[2][t] + pacc[6][t];
        float fw = pacc[3][t] + pacc[7][t];
        *(float4*)(facc4 + n * 4) = make_float4(fx, fy, fz, fw);
        float inv = fw != 0.f ? 1.f / fw : 0.f;
        float c0 = fx * inv, c1 = fy * inv, c2 = fz * inv;
        float el = 0.f, er = 0.f;
        #pragma unroll
        for (int f = 0; f < 80; ++f) {
            float gg = c0 * sW[f] + c1 * sW[80 + f] + c2 * sW[160 + f] + sB[f];
            gg = gg > 0.f ? gg : 0.f;
            el += gg * sU[f];
            er += gg * sV[f];
        }
        el2[n] = el;
        er2iv[n * 2] = er;
    }
}

// e2 (den2): one block per chunk; entry = (rel<<16)|src. Writes invden in-place.
__global__ __launch_bounds__(1024) void k_e2d(const unsigned* __restrict__ dbin,
                                              const unsigned* __restrict__ gctr,
                                              const float* __restrict__ el2,
                                              float* __restrict__ er2iv) {
    __shared__ float sden[CH], sEr2[CH];
    int c = blockIdx.x, g = blockIdx.y, t = threadIdx.x;
    int base = c * CH;
    if (t < CH) {
        sden[t] = 0.f;
        sEr2[t] = (base + t < NN) ? er2iv[((size_t)g * NN + base + t) * 2] : 0.f;
    }
    __syncthreads();
    const float* el = el2 + (size_t)g * NN;
    const unsigned* seg = dbin + (size_t)(g * C + c) * CAP;
    unsigned size = gctr[g * C + c];
    if (size > CAP) size = CAP;
    for (unsigned i = t; i < size; i += 1024) {
        unsigned p = seg[i];
        unsigned rel = p >> 16;
        atomicAdd(&sden[rel], __expf(lrelu(el[p & 0xFFFFu] + sEr2[rel], 0.2f)));
    }
    __syncthreads();
    if (t < CH && base + t < NN) {
        float s = sden[t];
        er2iv[((size_t)g * NN + base + t) * 2 + 1] = s != 0.f ? 1.f / s : 0.f;
    }
}

// e3 (q): one block per src-chunk; entry = (rel<<16)|dst. Writes q directly.
__global__ __launch_bounds__(1024) void k_e3d(const unsigned* __restrict__ sbin,
                                              const unsigned* __restrict__ gctr,
                                              const float* __restrict__ el2,
                                              const float* __restrict__ er2iv,
                                              float* __restrict__ q) {
    __shared__ float sq[CH], sEl[CH];
    int c = blockIdx.x, g = blockIdx.y, t = threadIdx.x;
    int base = c * CH;
    if (t < CH) {
        sq[t] = 0.f;
        sEl[t] = (base + t < NN) ? el2[(size_t)g * NN + base + t] : 0.f;
    }
    __syncthreads();
    const float* er = er2iv + (size_t)g * NN * 2;
    const unsigned* seg = sbin + (size_t)(g * C + c) * CAP;
    unsigned size = gctr[(2 + g) * C + c];
    if (size > CAP) size = CAP;
    for (unsigned i = t; i < size; i += 1024) {
        unsigned p = seg[i];
        unsigned rel = p >> 16;
        float2 E = *(const float2*)(er + 2 * (size_t)(p & 0xFFFFu));
        atomicAdd(&sq[rel], __expf(lrelu(sEl[rel] + E.x, 0.2f)) * E.y);
    }
    __syncthreads();
    if (t < CH && base + t < NN) q[g * NN + base + t] = sq[t];
}

// A[g][0..79] = sum_n q[n] * g1[n]
#define RT 128
__global__ void k_r(const float* __restrict__ facc4, const float* __restrict__ W1,
                    const float* __restrict__ b1, const float* __restrict__ q,
                    float* __restrict__ A) {
    __shared__ float4 sF[RT];
    __shared__ float sQ[RT];
    __shared__ float sW[240], sB[80];
    __shared__ float sA[240];
    int t = threadIdx.x;
    for (int i = t; i < 80; i += 256) {
        sW[i] = W1[i];
        sW[80 + i] = W1[160 + i];
        sW[160 + i] = W1[320 + i];
        sB[i] = b1[i];
    }
    int g = blockIdx.y;
    int grp = t / 80, f = t - grp * 80;
    float acc = 0.f;
    for (int n0 = blockIdx.x * RT; n0 < NN; n0 += gridDim.x * RT) {
        __syncthreads();
        if (t < RT) {
            int n = n0 + t;
            sF[t] = (n < NN) ? *(const float4*)(facc4 + ((size_t)g * NN + n) * 4)
                             : make_float4(0.f, 0.f, 0.f, 0.f);
        } else if (t < 2 * RT) {
            int n = n0 + t - RT;
            sQ[t - RT] = (n < NN) ? q[g * NN + n] : 0.f;
        }
        __syncthreads();
        if (grp < 3) {
            for (int i = grp; i < RT; i += 3) {
                float qn = sQ[i];
                if (qn == 0.f) continue;
                float4 fa = sF[i];
                float inv = fa.w != 0.f ? 1.f / fa.w : 0.f;
                float c0 = fa.x * inv, c1 = fa.y * inv, c2 = fa.z * inv;
                float gg = c0 * sW[f] + c1 * sW[80 + f] + c2 * sW[160 + f] + sB[f];
                gg = gg > 0.f ? gg : 0.f;
                acc += qn * gg;
            }
        }
    }
    if (grp < 3) sA[t] = acc;
    __syncthreads();
    if (t < 80) atomicAdd(&A[g * 80 + t], sA[t] + sA[80 + t] + sA[160 + t]);
}

// Final head (+ image conv tail). 256 threads.
__global__ void k_final(const float* __restrict__ A, const float* __restrict__ W2g,
                        const float* __restrict__ b2, const float* __restrict__ Wg1,
                        const float* __restrict__ bg1, const float* __restrict__ emb_acc,
                        const float* __restrict__ Wc1, const float* __restrict__ Wc2,
                        const float* __restrict__ vocab, const float* __restrict__ W2f,
                        const float* __restrict__ W3, float* __restrict__ out, int out_size) {
    __shared__ float emb[60];
    __shared__ float hh[80 * 30];
    __shared__ float a[60];
    __shared__ float hc[70];
    __shared__ float tt[80];
    __shared__ float lp[2];
    int t = threadIdx.x;
    if (t < 60) {
        emb[t] = emb_acc[t];
        int i = t / 30, j = t % 30;
        float acc = 0.f;
        for (int f = 0; f < 80; ++f) acc += A[i * 80 + f] * W2g[f * 60 + j];
        a[t] = acc * (1.f / NN) + b2[j];
    }
    __syncthreads();
    for (int p = t; p < 2400; p += 256) {
        int i = p / 30, j = p % 30;
        float v = Wc1[i * 2 + 0] * emb[j] + Wc1[i * 2 + 1] * emb[30 + j];
        hh[p] = lrelu(v, 0.01f);
    }
    __syncthreads();
    if (t < 30) {
        float acc = 0.f;
        for (int i = 0; i < 80; ++i) acc += Wc2[i] * hh[i * 30 + t];
        hc[30 + t] = lrelu(acc, 0.01f);
        float acg = bg1[t];
        for (int j = 0; j < 60; ++j) acg += a[j] * Wg1[j * 30 + t];
        hc[t] = acg;
        if (t < 10) hc[60 + t] = vocab[t];
    }
    __syncthreads();
    if (t < 80) {
        float acc = 0.f;
        for (int qd = 0; qd < 70; ++qd) acc += hc[qd] * W2f[qd * 80 + t];
        tt[t] = acc;
    }
    __syncthreads();
    if (t < 2) {
        float acc = 0.f;
        for (int p = 0; p < 80; ++p) acc += tt[p] * W3[p * 2 + t];
        lp[t] = acc;
    }
    __syncthreads();
    if (t == 0) {
        float m = fmaxf(lp[0], lp[1]);
        float lse = m + logf(expf(lp[0] - m) + expf(lp[1] - m));
        out[0] = lp[0] - lse;
        out[1] = lp[1] - lse;
    }
    for (int i = 2 + t; i < out_size; i += blockDim.x) out[i] = 0.f;
}

extern "C" void kernel_launch(void* const* d_in, const int* in_sizes, int n_in,
                              void* d_out, int out_size, void* d_ws, size_t ws_size,
                              hipStream_t stream) {
    const float* x        = (const float*)d_in[0];
    const float* vocab    = (const float*)d_in[1];
    const float* nodef    = (const float*)d_in[2];
    const int*   src      = (const int*)d_in[3];
    const int*   dst      = (const int*)d_in[4];
    const float* W_lin1   = (const float*)d_in[5];
    const float* Wc1      = (const float*)d_in[6];
    const float* Wc2      = (const float*)d_in[7];
    const float* gat1_W   = (const float*)d_in[8];
    const float* gat1_al  = (const float*)d_in[9];
    const float* gat1_ar  = (const float*)d_in[10];
    const float* gat1_b   = (const float*)d_in[11];
    const float* gat2_W   = (const float*)d_in[12];
    const float* gat2_al  = (const float*)d_in[13];
    const float* gat2_ar  = (const float*)d_in[14];
    const float* gat2_b   = (const float*)d_in[15];
    const float* Wg1      = (const float*)d_in[16];
    const float* bg1      = (const float*)d_in[17];
    const float* W2       = (const float*)d_in[18];
    const float* W3       = (const float*)d_in[19];
    (void)in_sizes; (void)n_in; (void)ws_size;

    float* w = (float*)d_ws;
    size_t off = 0;
    auto alloc = [&](size_t n) { size_t o = off; off += (n + 63) & ~(size_t)63; return o; };
    size_t o_emb  = alloc(64);    // zeroed
    size_t o_A    = alloc(192);   // zeroed
    size_t o_ctr  = alloc(1024);  // zeroed (4*C u32 bin counters)
    size_t o_feat = alloc((size_t)2 * NN * 4);
    size_t o_er1  = alloc(2 * NN);
    size_t o_el2  = alloc(2 * NN);
    size_t o_eriv = alloc((size_t)2 * NN * 2);
    size_t o_facc = alloc((size_t)2 * NN * 4);
    size_t o_q    = alloc(2 * NN);
    size_t o_dbin = alloc((size_t)2 * C * CAP);
    size_t o_sbin = alloc((size_t)2 * C * CAP);
    unsigned* gctr = (unsigned*)(w + o_ctr);
    unsigned* dbin = (unsigned*)(w + o_dbin);
    unsigned* sbin = (unsigned*)(w + o_sbin);

    hipMemsetAsync(w + o_emb, 0, (o_feat - o_emb) * sizeof(float), stream);
    // grid: 64 img + 392 pack + 1564 bin = 2020
    k_pre<<<2020, 256, 0, stream>>>(x, W_lin1, nodef, gat1_W, gat1_al, gat1_ar,
                                    src, dst, w + o_emb, w + o_feat, w + o_er1,
                                    gctr, dbin, sbin);

    k_e1n<<<dim3(C, 2), 1024, 0, stream>>>(dbin, gctr, w + o_feat, w + o_er1,
                                           gat1_W, gat1_b, gat2_W, gat2_al, gat2_ar,
                                           w + o_facc, w + o_el2, w + o_eriv);

    k_e2d<<<dim3(C, 2), 1024, 0, stream>>>(dbin, gctr, w + o_el2, w + o_eriv);

    k_e3d<<<dim3(C, 2), 1024, 0, stream>>>(sbin, gctr, w + o_el2, w + o_eriv, w + o_q);

    k_r<<<dim3(128, 2), 256, 0, stream>>>(w + o_facc, gat1_W, gat1_b, w + o_q, w + o_A);
    k_final<<<1, 256, 0, stream>>>(w + o_A, gat2_W, gat2_b, Wg1, bg1, w + o_emb,
                                   Wc1, Wc2, vocab, W2, W3, (float*)d_out, out_size);
}

// Round 19
// 100.814 us; speedup vs baseline: 2.0358x; 1.2487x over previous
//
#include <hip/hip_runtime.h>
#include <math.h>

#define NN 50000
#define NE 800000

#define CH 196              // nodes per chunk
#define C  256              // chunks (256*196 = 50176 >= NN); one block owns one chunk
#define CAP 3600            // per-bin capacity (mean 3125, sigma ~56)
#define BSL 2048            // bin edges per block

__device__ __forceinline__ float lrelu(float x, float s) { return x >= 0.f ? x : s * x; }

// Fused prologue. Blocks [0,64): image matmul partials. [64,456): per-node pack.
// [456,2020): counting-sort binning from int32; entry = (rel<<16)|partner.
__global__ void k_pre(const float* __restrict__ x, const float* __restrict__ Wl,
                      const float* __restrict__ nodef,
                      const float* __restrict__ W1, const float* __restrict__ al1,
                      const float* __restrict__ ar1,
                      const int* __restrict__ src, const int* __restrict__ dst,
                      float* __restrict__ imgp, float* __restrict__ feat4,
                      float* __restrict__ er1, unsigned* __restrict__ gctr,
                      unsigned* __restrict__ dbin, unsigned* __restrict__ sbin) {
    int bid = blockIdx.x, t = threadIdx.x;
    if (bid < 64) {
        __shared__ float part[8][64];
        int kk = t & 31, rq = t >> 5;
        int r0 = bid * 64;
        float a0 = 0.f, a1 = 0.f;
        if (kk < 30) {
            for (int i = 0; i < 8; ++i) {
                int r = r0 + rq * 8 + i;
                float wv = Wl[r * 30 + kk];
                a0 += x[r] * wv;
                a1 += x[4096 + r] * wv;
            }
        }
        part[rq][kk] = a0;
        part[rq][32 + kk] = a1;
        __syncthreads();
        if (t < 60) {
            int g = t / 30, k = t - g * 30;
            float s = 0.f;
            #pragma unroll
            for (int rr = 0; rr < 8; ++rr) s += part[rr][g * 32 + k];
            imgp[bid * 64 + g * 32 + k] = s;   // unconditional partial, no zero needed
        }
    } else if (bid < 456) {
        __shared__ float sP[6];
        if (t < 6) {
            int c = t >> 1;
            const float* av = (t & 1) ? ar1 : al1;
            float s = 0.f;
            for (int f = 0; f < 80; ++f) s += W1[c * 160 + f] * av[f];
            sP[(t & 1) * 3 + c] = s;
        }
        __syncthreads();
        int b2 = bid - 64;
        int g = b2 / 196;
        int n = (b2 - g * 196) * 256 + t;
        if (n < NN) {
            const float* f = nodef + ((size_t)g * NN + n) * 3;
            float f0 = f[0], f1 = f[1], f2 = f[2];
            *(float4*)(feat4 + ((size_t)g * NN + n) * 4) =
                make_float4(f0, f1, f2, f0 * sP[0] + f1 * sP[1] + f2 * sP[2]);
            er1[g * NN + n] = f0 * sP[3] + f1 * sP[4] + f2 * sP[5];
        }
    } else {
        __shared__ unsigned wcnt[4][C];
        __shared__ unsigned wbase[4][C];
        __shared__ unsigned wrun[4][C];
        __shared__ unsigned sbase2[C];
        int b3 = bid - 456;
        int a = b3 / 782;
        int rem2 = b3 - a * 782;
        int g = rem2 / 391;
        int bx = rem2 - g * 391;
        int wid = t >> 6;
        for (int i = t; i < 4 * C; i += 256) ((unsigned*)wcnt)[i] = 0;
        __syncthreads();
        const int* ip = (a ? src : dst) + (size_t)g * NE;
        const int* pp = (a ? dst : src) + (size_t)g * NE;
        unsigned* bin = (a ? sbin : dbin);
        int cbase = (a * 2 + g) * C;
        int bbase = g * C;
        int e0 = bx * BSL + t * 8;
        int nv = 0;
        if (e0 < NE) nv = (NE - e0) < 8 ? (NE - e0) : 8;
        unsigned cj[8], pk[8];
        if (nv == 8) {
            int4 v0 = *(const int4*)(ip + e0), v1 = *(const int4*)(ip + e0 + 4);
            int4 q0 = *(const int4*)(pp + e0), q1 = *(const int4*)(pp + e0 + 4);
            int dj[8] = {v0.x, v0.y, v0.z, v0.w, v1.x, v1.y, v1.z, v1.w};
            int pj[8] = {q0.x, q0.y, q0.z, q0.w, q1.x, q1.y, q1.z, q1.w};
            #pragma unroll
            for (int j = 0; j < 8; ++j) {
                unsigned c = (unsigned)dj[j] / CH;
                cj[j] = c;
                pk[j] = (((unsigned)dj[j] - c * CH) << 16) | (unsigned)pj[j];
                atomicAdd(&wcnt[wid][c], 1u);
            }
        } else {
            for (int j = 0; j < nv; ++j) {
                int dv = ip[e0 + j], pv = pp[e0 + j];
                unsigned c = (unsigned)dv / CH;
                cj[j] = c;
                pk[j] = (((unsigned)dv - c * CH) << 16) | (unsigned)pv;
                atomicAdd(&wcnt[wid][c], 1u);
            }
        }
        __syncthreads();
        if (t < C) {
            unsigned s = wcnt[0][t] + wcnt[1][t] + wcnt[2][t] + wcnt[3][t];
            sbase2[t] = atomicAdd(&gctr[cbase + t], s);
        }
        __syncthreads();
        for (int i = t; i < 4 * C; i += 256) {
            int w2 = i / C, b = i - w2 * C;
            unsigned off2 = 0;
            for (int w3 = 0; w3 < w2; ++w3) off2 += wcnt[w3][b];
            wbase[w2][b] = sbase2[b] + off2;
            wrun[w2][b] = 0;
        }
        __syncthreads();
        for (int j = 0; j < nv; ++j) {
            unsigned c = cj[j];
            unsigned slot = atomicAdd(&wrun[wid][c], 1u);
            unsigned pos = wbase[wid][c] + slot;
            if (pos < CAP) bin[(size_t)(bbase + c) * CAP + pos] = pk[j];
        }
    }
}

// e1 + node stage, via in-LDS counting sort + register accumulation (no float LDS atomics).
__global__ __launch_bounds__(1024) void k_e1n(const unsigned* __restrict__ dbin,
                                              const unsigned* __restrict__ gctr,
                                              const float* __restrict__ feat4,
                                              const float* __restrict__ er1,
                                              const float* __restrict__ W1,
                                              const float* __restrict__ b1,
                                              const float* __restrict__ W2,
                                              const float* __restrict__ al2,
                                              const float* __restrict__ ar2,
                                              float* __restrict__ facc4,
                                              float* __restrict__ el2,
                                              float* __restrict__ er2iv) {
    __shared__ unsigned scnt[CH];
    __shared__ unsigned sstart[CH + 1];
    __shared__ unsigned sofs[CH];
    __shared__ unsigned ssort[CAP];
    __shared__ float sEr[CH];
    __shared__ float pacc[8][CH];
    __shared__ float sW[240], sB[80], sU[80], sV[80];
    int c = blockIdx.x, g = blockIdx.y, t = threadIdx.x;
    int base = c * CH;
    if (t < CH) {
        scnt[t] = 0;
        sEr[t] = (base + t < NN) ? er1[(size_t)g * NN + base + t] : 0.f;
    }
    if (t >= 1024 - 80) {
        int f = t - (1024 - 80);
        sW[f] = W1[f];
        sW[80 + f] = W1[160 + f];
        sW[160 + f] = W1[320 + f];
        sB[f] = b1[f];
        float u = 0.f, v = 0.f;
        for (int j = 0; j < 30; ++j) {
            float wv = W2[f * 60 + j];
            u += wv * al2[j];
            v += wv * ar2[j];
        }
        sU[f] = u;
        sV[f] = v;
    }
    __syncthreads();
    const unsigned* seg = dbin + (size_t)(g * C + c) * CAP;
    unsigned size = gctr[g * C + c];
    if (size > CAP) size = CAP;
    for (unsigned i = t; i < size; i += 1024) atomicAdd(&scnt[seg[i] >> 16], 1u);
    __syncthreads();
    if (t == 0) {
        unsigned run = 0;
        for (int j = 0; j < CH; ++j) { sstart[j] = run; run += scnt[j]; }
        sstart[CH] = run;
    }
    __syncthreads();
    if (t < CH) sofs[t] = sstart[t];
    __syncthreads();
    for (unsigned i = t; i < size; i += 1024) {
        unsigned p = seg[i];
        unsigned slot = atomicAdd(&sofs[p >> 16], 1u);
        ssort[slot] = p & 0xFFFFu;
    }
    __syncthreads();
    const float* f4 = feat4 + (size_t)g * NN * 4;
    if (t < 2 * CH) {
        int rel = t >> 1, half = t & 1;
        unsigned start = sstart[rel], end = sstart[rel + 1];
        unsigned mid = (start + end) >> 1;
        unsigned lo = half ? mid : start;
        unsigned hi = half ? end : mid;
        float ax = 0.f, ay = 0.f, az = 0.f, aw = 0.f;
        float erv = sEr[rel];
        for (unsigned j = lo; j < hi; ++j) {
            unsigned s = ssort[j];
            float4 F = *(const float4*)(f4 + (size_t)s * 4);
            float wv = __expf(lrelu(F.w + erv, 0.2f));
            ax += wv * F.x; ay += wv * F.y; az += wv * F.z; aw += wv;
        }
        int hb = half * 4;
        pacc[hb + 0][rel] = ax;
        pacc[hb + 1][rel] = ay;
        pacc[hb + 2][rel] = az;
        pacc[hb + 3][rel] = aw;
    }
    __syncthreads();
    if (t < CH && base + t < NN) {
        size_t n = (size_t)g * NN + base + t;
        float fx = pacc[0][t] + pacc[4][t];
        float fy = pacc[1][t] + pacc[5][t];
        float fz = pacc[2][t] + pacc[6][t];
        float fw = pacc[3][t] + pacc[7][t];
        *(float4*)(facc4 + n * 4) = make_float4(fx, fy, fz, fw);
        float inv = fw != 0.f ? 1.f / fw : 0.f;
        float c0 = fx * inv, c1 = fy * inv, c2 = fz * inv;
        float el = 0.f, er = 0.f;
        #pragma unroll
        for (int f = 0; f < 80; ++f) {
            float gg = c0 * sW[f] + c1 * sW[80 + f] + c2 * sW[160 + f] + sB[f];
            gg = gg > 0.f ? gg : 0.f;
            el += gg * sU[f];
            er += gg * sV[f];
        }
        el2[n] = el;
        er2iv[n * 2] = er;
    }
}

// e2 (den2): one block per chunk; entry = (rel<<16)|src. Writes invden in-place.
__global__ __launch_bounds__(1024) void k_e2d(const unsigned* __restrict__ dbin,
                                              const unsigned* __restrict__ gctr,
                                              const float* __restrict__ el2,
                                              float* __restrict__ er2iv) {
    __shared__ float sden[CH], sEr2[CH];
    int c = blockIdx.x, g = blockIdx.y, t = threadIdx.x;
    int base = c * CH;
    if (t < CH) {
        sden[t] = 0.f;
        sEr2[t] = (base + t < NN) ? er2iv[((size_t)g * NN + base + t) * 2] : 0.f;
    }
    __syncthreads();
    const float* el = el2 + (size_t)g * NN;
    const unsigned* seg = dbin + (size_t)(g * C + c) * CAP;
    unsigned size = gctr[g * C + c];
    if (size > CAP) size = CAP;
    for (unsigned i = t; i < size; i += 1024) {
        unsigned p = seg[i];
        unsigned rel = p >> 16;
        atomicAdd(&sden[rel], __expf(lrelu(el[p & 0xFFFFu] + sEr2[rel], 0.2f)));
    }
    __syncthreads();
    if (t < CH && base + t < NN) {
        float s = sden[t];
        er2iv[((size_t)g * NN + base + t) * 2 + 1] = s != 0.f ? 1.f / s : 0.f;
    }
}

// e3 (q) + fused A-partials. One block per src-chunk.
// Phase 1: sq[rel] += exp(lrelu(el2[s]+er2[d])) * invden2[d].
// Phase 2: Apart[(g*C+c)*80+f] = sum_{rel} sq[rel] * g1[base+rel][f]  (register acc).
__global__ __launch_bounds__(1024) void k_e3q(const unsigned* __restrict__ sbin,
                                              const unsigned* __restrict__ gctr,
                                              const float* __restrict__ el2,
                                              const float* __restrict__ er2iv,
                                              const float* __restrict__ facc4,
                                              const float* __restrict__ W1,
                                              const float* __restrict__ b1,
                                              float* __restrict__ Apart) {
    __shared__ float sq[CH], sEl[CH];
    __shared__ float cx[CH], cy[CH], cz[CH];
    __shared__ float pacc2[12][80];
    __shared__ float sW[240], sB[80];
    int c = blockIdx.x, g = blockIdx.y, t = threadIdx.x;
    int base = c * CH;
    if (t < CH) {
        sq[t] = 0.f;
        sEl[t] = (base + t < NN) ? el2[(size_t)g * NN + base + t] : 0.f;
    }
    if (t >= 1024 - 80) {
        int f = t - (1024 - 80);
        sW[f] = W1[f];
        sW[80 + f] = W1[160 + f];
        sW[160 + f] = W1[320 + f];
        sB[f] = b1[f];
    }
    __syncthreads();
    const float* er = er2iv + (size_t)g * NN * 2;
    const unsigned* seg = sbin + (size_t)(g * C + c) * CAP;
    unsigned size = gctr[(2 + g) * C + c];
    if (size > CAP) size = CAP;
    for (unsigned i = t; i < size; i += 1024) {
        unsigned p = seg[i];
        unsigned rel = p >> 16;
        float2 E = *(const float2*)(er + 2 * (size_t)(p & 0xFFFFu));
        atomicAdd(&sq[rel], __expf(lrelu(sEl[rel] + E.x, 0.2f)) * E.y);
    }
    __syncthreads();
    if (t < CH) {
        if (base + t < NN) {
            float4 fa = *(const float4*)(facc4 + ((size_t)g * NN + base + t) * 4);
            float inv = fa.w != 0.f ? 1.f / fa.w : 0.f;
            cx[t] = fa.x * inv; cy[t] = fa.y * inv; cz[t] = fa.z * inv;
        } else {
            cx[t] = 0.f; cy[t] = 0.f; cz[t] = 0.f;
        }
    }
    __syncthreads();
    int grp = t / 80, f = t - grp * 80;
    if (grp < 12) {
        float acc = 0.f;
        float wf0 = sW[f], wf1 = sW[80 + f], wf2 = sW[160 + f], bf = sB[f];
        for (int i = grp; i < CH; i += 12) {
            float qn = sq[i];
            float gg = cx[i] * wf0 + cy[i] * wf1 + cz[i] * wf2 + bf;
            gg = gg > 0.f ? gg : 0.f;
            acc += qn * gg;
        }
        pacc2[grp][f] = acc;
    }
    __syncthreads();
    if (t < 80) {
        float s = 0.f;
        #pragma unroll
        for (int j = 0; j < 12; ++j) s += pacc2[j][t];
        Apart[((size_t)g * C + c) * 80 + t] = s;
    }
}

// Final head: sum img partials + A partials, conv tail, tiny matmuls, log_softmax.
__global__ void k_final(const float* __restrict__ Apart, const float* __restrict__ imgp,
                        const float* __restrict__ W2g, const float* __restrict__ b2,
                        const float* __restrict__ Wg1, const float* __restrict__ bg1,
                        const float* __restrict__ Wc1, const float* __restrict__ Wc2,
                        const float* __restrict__ vocab, const float* __restrict__ W2f,
                        const float* __restrict__ W3, float* __restrict__ out, int out_size) {
    __shared__ float sA[160];
    __shared__ float emb[60];
    __shared__ float hh[80 * 30];
    __shared__ float a[60];
    __shared__ float hc[70];
    __shared__ float tt[80];
    __shared__ float lp[2];
    int t = threadIdx.x;  // 256
    if (t < 160) {
        int g = t / 80, f = t - g * 80;
        float s = 0.f;
        const float* Ap = Apart + (size_t)g * C * 80 + f;
        for (int c = 0; c < C; ++c) s += Ap[(size_t)c * 80];
        sA[t] = s;
    } else if (t < 220) {
        int q = t - 160;  // 60: g*30+j
        int g = q / 30, j = q - g * 30;
        float s = 0.f;
        for (int b = 0; b < 64; ++b) s += imgp[b * 64 + g * 32 + j];
        emb[q] = s;
    }
    __syncthreads();
    if (t < 60) {
        int i = t / 30, j = t % 30;
        float acc = 0.f;
        for (int f = 0; f < 80; ++f) acc += sA[i * 80 + f] * W2g[f * 60 + j];
        a[t] = acc * (1.f / NN) + b2[j];
    }
    __syncthreads();
    for (int p = t; p < 2400; p += 256) {
        int i = p / 30, j = p % 30;
        float v = Wc1[i * 2 + 0] * emb[j] + Wc1[i * 2 + 1] * emb[30 + j];
        hh[p] = lrelu(v, 0.01f);
    }
    __syncthreads();
    if (t < 30) {
        float acc = 0.f;
        for (int i = 0; i < 80; ++i) acc += Wc2[i] * hh[i * 30 + t];
        hc[30 + t] = lrelu(acc, 0.01f);
        float acg = bg1[t];
        for (int j = 0; j < 60; ++j) acg += a[j] * Wg1[j * 30 + t];
        hc[t] = acg;
        if (t < 10) hc[60 + t] = vocab[t];
    }
    __syncthreads();
    if (t < 80) {
        float acc = 0.f;
        for (int qd = 0; qd < 70; ++qd) acc += hc[qd] * W2f[qd * 80 + t];
        tt[t] = acc;
    }
    __syncthreads();
    if (t < 2) {
        float acc = 0.f;
        for (int p = 0; p < 80; ++p) acc += tt[p] * W3[p * 2 + t];
        lp[t] = acc;
    }
    __syncthreads();
    if (t == 0) {
        float m = fmaxf(lp[0], lp[1]);
        float lse = m + logf(expf(lp[0] - m) + expf(lp[1] - m));
        out[0] = lp[0] - lse;
        out[1] = lp[1] - lse;
    }
    for (int i = 2 + t; i < out_size; i += blockDim.x) out[i] = 0.f;
}

extern "C" void kernel_launch(void* const* d_in, const int* in_sizes, int n_in,
                              void* d_out, int out_size, void* d_ws, size_t ws_size,
                              hipStream_t stream) {
    const float* x        = (const float*)d_in[0];
    const float* vocab    = (const float*)d_in[1];
    const float* nodef    = (const float*)d_in[2];
    const int*   src      = (const int*)d_in[3];
    const int*   dst      = (const int*)d_in[4];
    const float* W_lin1   = (const float*)d_in[5];
    const float* Wc1      = (const float*)d_in[6];
    const float* Wc2      = (const float*)d_in[7];
    const float* gat1_W   = (const float*)d_in[8];
    const float* gat1_al  = (const float*)d_in[9];
    const float* gat1_ar  = (const float*)d_in[10];
    const float* gat1_b   = (const float*)d_in[11];
    const float* gat2_W   = (const float*)d_in[12];
    const float* gat2_al  = (const float*)d_in[13];
    const float* gat2_ar  = (const float*)d_in[14];
    const float* gat2_b   = (const float*)d_in[15];
    const float* Wg1      = (const float*)d_in[16];
    const float* bg1      = (const float*)d_in[17];
    const float* W2       = (const float*)d_in[18];
    const float* W3       = (const float*)d_in[19];
    (void)in_sizes; (void)n_in; (void)ws_size;

    float* w = (float*)d_ws;
    size_t off = 0;
    auto alloc = [&](size_t n) { size_t o = off; off += (n + 63) & ~(size_t)63; return o; };
    size_t o_ctr  = alloc(1024);  // zeroed (4*C u32 bin counters)
    size_t o_imgp = alloc(64 * 64);
    size_t o_Ap   = alloc((size_t)2 * C * 80);
    size_t o_feat = alloc((size_t)2 * NN * 4);
    size_t o_er1  = alloc(2 * NN);
    size_t o_el2  = alloc(2 * NN);
    size_t o_eriv = alloc((size_t)2 * NN * 2);
    size_t o_facc = alloc((size_t)2 * NN * 4);
    size_t o_dbin = alloc((size_t)2 * C * CAP);
    size_t o_sbin = alloc((size_t)2 * C * CAP);
    unsigned* gctr = (unsigned*)(w + o_ctr);
    unsigned* dbin = (unsigned*)(w + o_dbin);
    unsigned* sbin = (unsigned*)(w + o_sbin);

    hipMemsetAsync(w + o_ctr, 0, 1024 * sizeof(float), stream);
    // grid: 64 img + 392 pack + 1564 bin = 2020
    k_pre<<<2020, 256, 0, stream>>>(x, W_lin1, nodef, gat1_W, gat1_al, gat1_ar,
                                    src, dst, w + o_imgp, w + o_feat, w + o_er1,
                                    gctr, dbin, sbin);

    k_e1n<<<dim3(C, 2), 1024, 0, stream>>>(dbin, gctr, w + o_feat, w + o_er1,
                                           gat1_W, gat1_b, gat2_W, gat2_al, gat2_ar,
                                           w + o_facc, w + o_el2, w + o_eriv);

    k_e2d<<<dim3(C, 2), 1024, 0, stream>>>(dbin, gctr, w + o_el2, w + o_eriv);

    k_e3q<<<dim3(C, 2), 1024, 0, stream>>>(sbin, gctr, w + o_el2, w + o_eriv,
                                           w + o_facc, gat1_W, gat1_b, w + o_Ap);

    k_final<<<1, 256, 0, stream>>>(w + o_Ap, w + o_imgp, gat2_W, gat2_b, Wg1, bg1,
                                   Wc1, Wc2, vocab, W2, W3, (float*)d_out, out_size);
}

// Round 20
// 85.643 us; speedup vs baseline: 2.3964x; 1.1771x over previous
//
#include <hip/hip_runtime.h>
#include <math.h>

#define NN 50000
#define NE 800000

#define CH 196              // nodes per chunk
#define C  256              // chunks (256*196 = 50176 >= NN); one block owns one chunk
#define CAP 3600            // per-bin capacity (mean 3125, sigma ~56)
#define BSL 8192            // bin edges per block (block-level sort)

__device__ __forceinline__ float lrelu(float x, float s) { return x >= 0.f ? x : s * x; }

// Fused prologue, 1024-thread blocks.
// [0,16): image matmul partials. [16,114): per-node pack. [114,506): sorted binning.
__global__ __launch_bounds__(1024) void k_pre(
        const float* __restrict__ x, const float* __restrict__ Wl,
        const float* __restrict__ nodef,
        const float* __restrict__ W1, const float* __restrict__ al1,
        const float* __restrict__ ar1,
        const int* __restrict__ src, const int* __restrict__ dst,
        float* __restrict__ imgp, float* __restrict__ feat4,
        float* __restrict__ er1, unsigned* __restrict__ gctr,
        unsigned* __restrict__ dbin, unsigned* __restrict__ sbin) {
    int bid = blockIdx.x, t = threadIdx.x;
    if (bid < 16) {
        __shared__ float part[32][64];
        int kk = t & 31, rq = t >> 5;   // 32 row-quads
        int r0 = bid * 256;
        float a0 = 0.f, a1 = 0.f;
        if (kk < 30) {
            for (int i = 0; i < 8; ++i) {
                int r = r0 + rq * 8 + i;
                float wv = Wl[r * 30 + kk];
                a0 += x[r] * wv;
                a1 += x[4096 + r] * wv;
            }
        }
        part[rq][kk] = a0;
        part[rq][32 + kk] = a1;
        __syncthreads();
        if (t < 60) {
            int g = t / 30, k = t - g * 30;
            float s = 0.f;
            #pragma unroll
            for (int rr = 0; rr < 32; ++rr) s += part[rr][g * 32 + k];
            imgp[bid * 64 + g * 32 + k] = s;
        }
    } else if (bid < 114) {
        __shared__ float sP[6];
        if (t < 6) {
            int c = t >> 1;
            const float* av = (t & 1) ? ar1 : al1;
            float s = 0.f;
            for (int f = 0; f < 80; ++f) s += W1[c * 160 + f] * av[f];
            sP[(t & 1) * 3 + c] = s;
        }
        __syncthreads();
        int flat = (bid - 16) * 1024 + t;
        if (flat < 2 * NN) {
            int g = flat / NN;
            int n = flat - g * NN;
            const float* f = nodef + (size_t)flat * 3;
            float f0 = f[0], f1 = f[1], f2 = f[2];
            *(float4*)(feat4 + (size_t)flat * 4) =
                make_float4(f0, f1, f2, f0 * sP[0] + f1 * sP[1] + f2 * sP[2]);
            er1[g * NN + n] = f0 * sP[3] + f1 * sP[4] + f2 * sP[5];
        }
    } else {
        // Block-level counting-sort binning. entry = (c<<24)|(rel<<16)|partner.
        __shared__ unsigned scnt[C];
        __shared__ unsigned sstart[C + 1];
        __shared__ unsigned sbase[C];
        __shared__ unsigned sofs[C];
        __shared__ unsigned ssort[BSL];
        int b3 = bid - 114;
        int a = b3 / 196;
        int rem = b3 - a * 196;
        int g = rem / 98;
        int bx = rem - g * 98;
        if (t < C) scnt[t] = 0;
        __syncthreads();
        const int* ip = (a ? src : dst) + (size_t)g * NE;
        const int* pp = (a ? dst : src) + (size_t)g * NE;
        unsigned* bin = (a ? sbin : dbin);
        int cbase = (a * 2 + g) * C;
        int bbase = g * C;
        int e0 = bx * BSL + t * 8;
        int nv = 0;
        if (e0 < NE) nv = (NE - e0) < 8 ? (NE - e0) : 8;
        unsigned pk[8];
        if (nv == 8) {
            int4 v0 = *(const int4*)(ip + e0), v1 = *(const int4*)(ip + e0 + 4);
            int4 q0 = *(const int4*)(pp + e0), q1 = *(const int4*)(pp + e0 + 4);
            int dj[8] = {v0.x, v0.y, v0.z, v0.w, v1.x, v1.y, v1.z, v1.w};
            int pj[8] = {q0.x, q0.y, q0.z, q0.w, q1.x, q1.y, q1.z, q1.w};
            #pragma unroll
            for (int j = 0; j < 8; ++j) {
                unsigned c = (unsigned)dj[j] / CH;
                pk[j] = (c << 24) | (((unsigned)dj[j] - c * CH) << 16) | (unsigned)pj[j];
                atomicAdd(&scnt[c], 1u);
            }
        } else {
            for (int j = 0; j < nv; ++j) {
                int dv = ip[e0 + j], pv = pp[e0 + j];
                unsigned c = (unsigned)dv / CH;
                pk[j] = (c << 24) | (((unsigned)dv - c * CH) << 16) | (unsigned)pv;
                atomicAdd(&scnt[c], 1u);
            }
        }
        __syncthreads();
        if (t == 0) {
            unsigned run = 0;
            for (int j = 0; j < C; ++j) { sstart[j] = run; run += scnt[j]; }
            sstart[C] = run;
        }
        __syncthreads();
        if (t < C) {
            sbase[t] = atomicAdd(&gctr[cbase + t], scnt[t]);
            sofs[t] = sstart[t];
        }
        __syncthreads();
        for (int j = 0; j < nv; ++j) {
            unsigned c = pk[j] >> 24;
            unsigned slot = atomicAdd(&sofs[c], 1u);
            ssort[slot] = pk[j];
        }
        __syncthreads();
        unsigned total = sstart[C];
        for (unsigned i = t; i < total; i += 1024) {
            unsigned v = ssort[i];
            unsigned c = v >> 24;
            unsigned pos = sbase[c] + (i - sstart[c]);
            if (pos < CAP) bin[(size_t)(bbase + c) * CAP + pos] = v & 0xFFFFFFu;
        }
    }
}

// e1 + node stage, via in-LDS counting sort + register accumulation (no float LDS atomics).
__global__ __launch_bounds__(1024) void k_e1n(const unsigned* __restrict__ dbin,
                                              const unsigned* __restrict__ gctr,
                                              const float* __restrict__ feat4,
                                              const float* __restrict__ er1,
                                              const float* __restrict__ W1,
                                              const float* __restrict__ b1,
                                              const float* __restrict__ W2,
                                              const float* __restrict__ al2,
                                              const float* __restrict__ ar2,
                                              float* __restrict__ facc4,
                                              float* __restrict__ el2,
                                              float* __restrict__ er2iv) {
    __shared__ unsigned scnt[CH];
    __shared__ unsigned sstart[CH + 1];
    __shared__ unsigned sofs[CH];
    __shared__ unsigned ssort[CAP];
    __shared__ float sEr[CH];
    __shared__ float pacc[8][CH];
    __shared__ float sW[240], sB[80], sU[80], sV[80];
    int c = blockIdx.x, g = blockIdx.y, t = threadIdx.x;
    int base = c * CH;
    if (t < CH) {
        scnt[t] = 0;
        sEr[t] = (base + t < NN) ? er1[(size_t)g * NN + base + t] : 0.f;
    }
    if (t >= 1024 - 80) {
        int f = t - (1024 - 80);
        sW[f] = W1[f];
        sW[80 + f] = W1[160 + f];
        sW[160 + f] = W1[320 + f];
        sB[f] = b1[f];
        float u = 0.f, v = 0.f;
        for (int j = 0; j < 30; ++j) {
            float wv = W2[f * 60 + j];
            u += wv * al2[j];
            v += wv * ar2[j];
        }
        sU[f] = u;
        sV[f] = v;
    }
    __syncthreads();
    const unsigned* seg = dbin + (size_t)(g * C + c) * CAP;
    unsigned size = gctr[g * C + c];
    if (size > CAP) size = CAP;
    for (unsigned i = t; i < size; i += 1024) atomicAdd(&scnt[seg[i] >> 16], 1u);
    __syncthreads();
    if (t == 0) {
        unsigned run = 0;
        for (int j = 0; j < CH; ++j) { sstart[j] = run; run += scnt[j]; }
        sstart[CH] = run;
    }
    __syncthreads();
    if (t < CH) sofs[t] = sstart[t];
    __syncthreads();
    for (unsigned i = t; i < size; i += 1024) {
        unsigned p = seg[i];
        unsigned slot = atomicAdd(&sofs[p >> 16], 1u);
        ssort[slot] = p & 0xFFFFu;
    }
    __syncthreads();
    const float* f4 = feat4 + (size_t)g * NN * 4;
    if (t < 2 * CH) {
        int rel = t >> 1, half = t & 1;
        unsigned start = sstart[rel], end = sstart[rel + 1];
        unsigned mid = (start + end) >> 1;
        unsigned lo = half ? mid : start;
        unsigned hi = half ? end : mid;
        float ax = 0.f, ay = 0.f, az = 0.f, aw = 0.f;
        float erv = sEr[rel];
        for (unsigned j = lo; j < hi; ++j) {
            unsigned s = ssort[j];
            float4 F = *(const float4*)(f4 + (size_t)s * 4);
            float wv = __expf(lrelu(F.w + erv, 0.2f));
            ax += wv * F.x; ay += wv * F.y; az += wv * F.z; aw += wv;
        }
        int hb = half * 4;
        pacc[hb + 0][rel] = ax;
        pacc[hb + 1][rel] = ay;
        pacc[hb + 2][rel] = az;
        pacc[hb + 3][rel] = aw;
    }
    __syncthreads();
    if (t < CH && base + t < NN) {
        size_t n = (size_t)g * NN + base + t;
        float fx = pacc[0][t] + pacc[4][t];
        float fy = pacc[1][t] + pacc[5][t];
        float fz = pacc[2][t] + pacc[6][t];
        float fw = pacc[3][t] + pacc[7][t];
        *(float4*)(facc4 + n * 4) = make_float4(fx, fy, fz, fw);
        float inv = fw != 0.f ? 1.f / fw : 0.f;
        float c0 = fx * inv, c1 = fy * inv, c2 = fz * inv;
        float el = 0.f, er = 0.f;
        #pragma unroll
        for (int f = 0; f < 80; ++f) {
            float gg = c0 * sW[f] + c1 * sW[80 + f] + c2 * sW[160 + f] + sB[f];
            gg = gg > 0.f ? gg : 0.f;
            el += gg * sU[f];
            er += gg * sV[f];
        }
        el2[n] = el;
        er2iv[n * 2] = er;
    }
}

// e2 (den2): one block per chunk; entry = (rel<<16)|src. Writes invden in-place.
__global__ __launch_bounds__(1024) void k_e2d(const unsigned* __restrict__ dbin,
                                              const unsigned* __restrict__ gctr,
                                              const float* __restrict__ el2,
                                              float* __restrict__ er2iv) {
    __shared__ float sden[CH], sEr2[CH];
    int c = blockIdx.x, g = blockIdx.y, t = threadIdx.x;
    int base = c * CH;
    if (t < CH) {
        sden[t] = 0.f;
        sEr2[t] = (base + t < NN) ? er2iv[((size_t)g * NN + base + t) * 2] : 0.f;
    }
    __syncthreads();
    const float* el = el2 + (size_t)g * NN;
    const unsigned* seg = dbin + (size_t)(g * C + c) * CAP;
    unsigned size = gctr[g * C + c];
    if (size > CAP) size = CAP;
    for (unsigned i = t; i < size; i += 1024) {
        unsigned p = seg[i];
        unsigned rel = p >> 16;
        atomicAdd(&sden[rel], __expf(lrelu(el[p & 0xFFFFu] + sEr2[rel], 0.2f)));
    }
    __syncthreads();
    if (t < CH && base + t < NN) {
        float s = sden[t];
        er2iv[((size_t)g * NN + base + t) * 2 + 1] = s != 0.f ? 1.f / s : 0.f;
    }
}

// e3 (q) + fused A-partials. One block per src-chunk.
__global__ __launch_bounds__(1024) void k_e3q(const unsigned* __restrict__ sbin,
                                              const unsigned* __restrict__ gctr,
                                              const float* __restrict__ el2,
                                              const float* __restrict__ er2iv,
                                              const float* __restrict__ facc4,
                                              const float* __restrict__ W1,
                                              const float* __restrict__ b1,
                                              float* __restrict__ Apart) {
    __shared__ float sq[CH], sEl[CH];
    __shared__ float cx[CH], cy[CH], cz[CH];
    __shared__ float pacc2[12][80];
    __shared__ float sW[240], sB[80];
    int c = blockIdx.x, g = blockIdx.y, t = threadIdx.x;
    int base = c * CH;
    if (t < CH) {
        sq[t] = 0.f;
        sEl[t] = (base + t < NN) ? el2[(size_t)g * NN + base + t] : 0.f;
    }
    if (t >= 1024 - 80) {
        int f = t - (1024 - 80);
        sW[f] = W1[f];
        sW[80 + f] = W1[160 + f];
        sW[160 + f] = W1[320 + f];
        sB[f] = b1[f];
    }
    __syncthreads();
    const float* er = er2iv + (size_t)g * NN * 2;
    const unsigned* seg = sbin + (size_t)(g * C + c) * CAP;
    unsigned size = gctr[(2 + g) * C + c];
    if (size > CAP) size = CAP;
    for (unsigned i = t; i < size; i += 1024) {
        unsigned p = seg[i];
        unsigned rel = p >> 16;
        float2 E = *(const float2*)(er + 2 * (size_t)(p & 0xFFFFu));
        atomicAdd(&sq[rel], __expf(lrelu(sEl[rel] + E.x, 0.2f)) * E.y);
    }
    __syncthreads();
    if (t < CH) {
        if (base + t < NN) {
            float4 fa = *(const float4*)(facc4 + ((size_t)g * NN + base + t) * 4);
            float inv = fa.w != 0.f ? 1.f / fa.w : 0.f;
            cx[t] = fa.x * inv; cy[t] = fa.y * inv; cz[t] = fa.z * inv;
        } else {
            cx[t] = 0.f; cy[t] = 0.f; cz[t] = 0.f;
        }
    }
    __syncthreads();
    int grp = t / 80, f = t - grp * 80;
    if (grp < 12) {
        float acc = 0.f;
        float wf0 = sW[f], wf1 = sW[80 + f], wf2 = sW[160 + f], bf = sB[f];
        for (int i = grp; i < CH; i += 12) {
            float qn = sq[i];
            float gg = cx[i] * wf0 + cy[i] * wf1 + cz[i] * wf2 + bf;
            gg = gg > 0.f ? gg : 0.f;
            acc += qn * gg;
        }
        pacc2[grp][f] = acc;
    }
    __syncthreads();
    if (t < 80) {
        float s = 0.f;
        #pragma unroll
        for (int j = 0; j < 12; ++j) s += pacc2[j][t];
        Apart[((size_t)g * C + c) * 80 + t] = s;
    }
}

// Final head: sum img partials + A partials, conv tail, tiny matmuls, log_softmax.
__global__ void k_final(const float* __restrict__ Apart, const float* __restrict__ imgp,
                        const float* __restrict__ W2g, const float* __restrict__ b2,
                        const float* __restrict__ Wg1, const float* __restrict__ bg1,
                        const float* __restrict__ Wc1, const float* __restrict__ Wc2,
                        const float* __restrict__ vocab, const float* __restrict__ W2f,
                        const float* __restrict__ W3, float* __restrict__ out, int out_size) {
    __shared__ float sA[160];
    __shared__ float emb[60];
    __shared__ float hh[80 * 30];
    __shared__ float a[60];
    __shared__ float hc[70];
    __shared__ float tt[80];
    __shared__ float lp[2];
    int t = threadIdx.x;  // 256
    if (t < 160) {
        int g = t / 80, f = t - g * 80;
        float s = 0.f;
        const float* Ap = Apart + (size_t)g * C * 80 + f;
        for (int c = 0; c < C; ++c) s += Ap[(size_t)c * 80];
        sA[t] = s;
    } else if (t < 220) {
        int q = t - 160;  // 60: g*30+j
        int g = q / 30, j = q - g * 30;
        float s = 0.f;
        for (int b = 0; b < 16; ++b) s += imgp[b * 64 + g * 32 + j];
        emb[q] = s;
    }
    __syncthreads();
    if (t < 60) {
        int i = t / 30, j = t % 30;
        float acc = 0.f;
        for (int f = 0; f < 80; ++f) acc += sA[i * 80 + f] * W2g[f * 60 + j];
        a[t] = acc * (1.f / NN) + b2[j];
    }
    __syncthreads();
    for (int p = t; p < 2400; p += 256) {
        int i = p / 30, j = p % 30;
        float v = Wc1[i * 2 + 0] * emb[j] + Wc1[i * 2 + 1] * emb[30 + j];
        hh[p] = lrelu(v, 0.01f);
    }
    __syncthreads();
    if (t < 30) {
        float acc = 0.f;
        for (int i = 0; i < 80; ++i) acc += Wc2[i] * hh[i * 30 + t];
        hc[30 + t] = lrelu(acc, 0.01f);
        float acg = bg1[t];
        for (int j = 0; j < 60; ++j) acg += a[j] * Wg1[j * 30 + t];
        hc[t] = acg;
        if (t < 10) hc[60 + t] = vocab[t];
    }
    __syncthreads();
    if (t < 80) {
        float acc = 0.f;
        for (int qd = 0; qd < 70; ++qd) acc += hc[qd] * W2f[qd * 80 + t];
        tt[t] = acc;
    }
    __syncthreads();
    if (t < 2) {
        float acc = 0.f;
        for (int p = 0; p < 80; ++p) acc += tt[p] * W3[p * 2 + t];
        lp[t] = acc;
    }
    __syncthreads();
    if (t == 0) {
        float m = fmaxf(lp[0], lp[1]);
        float lse = m + logf(expf(lp[0] - m) + expf(lp[1] - m));
        out[0] = lp[0] - lse;
        out[1] = lp[1] - lse;
    }
    for (int i = 2 + t; i < out_size; i += blockDim.x) out[i] = 0.f;
}

extern "C" void kernel_launch(void* const* d_in, const int* in_sizes, int n_in,
                              void* d_out, int out_size, void* d_ws, size_t ws_size,
                              hipStream_t stream) {
    const float* x        = (const float*)d_in[0];
    const float* vocab    = (const float*)d_in[1];
    const float* nodef    = (const float*)d_in[2];
    const int*   src      = (const int*)d_in[3];
    const int*   dst      = (const int*)d_in[4];
    const float* W_lin1   = (const float*)d_in[5];
    const float* Wc1      = (const float*)d_in[6];
    const float* Wc2      = (const float*)d_in[7];
    const float* gat1_W   = (const float*)d_in[8];
    const float* gat1_al  = (const float*)d_in[9];
    const float* gat1_ar  = (const float*)d_in[10];
    const float* gat1_b   = (const float*)d_in[11];
    const float* gat2_W   = (const float*)d_in[12];
    const float* gat2_al  = (const float*)d_in[13];
    const float* gat2_ar  = (const float*)d_in[14];
    const float* gat2_b   = (const float*)d_in[15];
    const float* Wg1      = (const float*)d_in[16];
    const float* bg1      = (const float*)d_in[17];
    const float* W2       = (const float*)d_in[18];
    const float* W3       = (const float*)d_in[19];
    (void)in_sizes; (void)n_in; (void)ws_size;

    float* w = (float*)d_ws;
    size_t off = 0;
    auto alloc = [&](size_t n) { size_t o = off; off += (n + 63) & ~(size_t)63; return o; };
    size_t o_ctr  = alloc(1024);  // zeroed (4*C u32 bin counters)
    size_t o_imgp = alloc(16 * 64);
    size_t o_Ap   = alloc((size_t)2 * C * 80);
    size_t o_feat = alloc((size_t)2 * NN * 4);
    size_t o_er1  = alloc(2 * NN);
    size_t o_el2  = alloc(2 * NN);
    size_t o_eriv = alloc((size_t)2 * NN * 2);
    size_t o_facc = alloc((size_t)2 * NN * 4);
    size_t o_dbin = alloc((size_t)2 * C * CAP);
    size_t o_sbin = alloc((size_t)2 * C * CAP);
    unsigned* gctr = (unsigned*)(w + o_ctr);
    unsigned* dbin = (unsigned*)(w + o_dbin);
    unsigned* sbin = (unsigned*)(w + o_sbin);

    hipMemsetAsync(w + o_ctr, 0, 1024 * sizeof(float), stream);
    // grid: 16 img + 98 pack + 392 bin = 506 blocks x 1024
    k_pre<<<506, 1024, 0, stream>>>(x, W_lin1, nodef, gat1_W, gat1_al, gat1_ar,
                                    src, dst, w + o_imgp, w + o_feat, w + o_er1,
                                    gctr, dbin, sbin);

    k_e1n<<<dim3(C, 2), 1024, 0, stream>>>(dbin, gctr, w + o_feat, w + o_er1,
                                           gat1_W, gat1_b, gat2_W, gat2_al, gat2_ar,
                                           w + o_facc, w + o_el2, w + o_eriv);

    k_e2d<<<dim3(C, 2), 1024, 0, stream>>>(dbin, gctr, w + o_el2, w + o_eriv);

    k_e3q<<<dim3(C, 2), 1024, 0, stream>>>(sbin, gctr, w + o_el2, w + o_eriv,
                                           w + o_facc, gat1_W, gat1_b, w + o_Ap);

    k_final<<<1, 256, 0, stream>>>(w + o_Ap, w + o_imgp, gat2_W, gat2_b, Wg1, bg1,
                                   Wc1, Wc2, vocab, W2, W3, (float*)d_out, out_size);
}